// Round 2
// 1248.007 us; speedup vs baseline: 1.0431x; 1.0431x over previous
//
#include <hip/hip_runtime.h>
#include <math.h>

// ---------------------------------------------------------------------------
// mTransformerConv: 2x TransformerConv (H=10, c=5 then c=1) + GraphNorm + relu
// N=100000, E=1600000, D_NODE=128, D_EDGE=32, G=64.
// Round 8 (= R7 + compile fix): k_qkvs1 rewritten — drop the 40KB sX LDS
// staging (x read straight from global, full 64B lines, L3-resident across
// y-groups); weights-only LDS (20.6KB) loaded once, ZERO in-loop barriers;
// __launch_bounds__(256,4) so all 784 blocks are co-resident (was 2 blocks/CU
// + 1.53 dispatch rounds = 17% occ). k_conv1 K-loop unrolled 2-wide with
// independent accumulators to overlap the per-edge dependent chain.
// ---------------------------------------------------------------------------

#define EPS 1e-5f
#define INV_SQRT5 0.44721359549995794f

__device__ __forceinline__ float f16_to_f32(unsigned short u) {
  union { unsigned short us; _Float16 h; } cv; cv.us = u;
  return (float)cv.h;
}

__device__ __forceinline__ void store40(const float (&acc)[40], int n, int g,
                                        float* __restrict__ q1, float* __restrict__ kv1,
                                        float* __restrict__ xr1) {
#pragma unroll
  for (int c = 0; c < 40; ++c) {
    int ch = g * 40 + c;
    if (ch < 50)        q1[(size_t)n * 52 + ch] = acc[c];
    else if (ch < 100)  kv1[(size_t)n * 104 + 2 * (ch - 50)] = acc[c];
    else if (ch < 150)  kv1[(size_t)n * 104 + 2 * (ch - 100) + 1] = acc[c];
    else if (ch < 155)  xr1[(size_t)n * 8 + (ch - 150)] = acc[c];
  }
}

// ---- K1: q1/kv1/xr1 GEMM. 512 nodes x 40 ch per block ----------------------
// Weights-only LDS (loaded once); x streamed from global per thread (2 nodes,
// contiguous 64B-line reads). No barriers in the K-loop.
__global__ __launch_bounds__(256, 4) void k_qkvs1(
    const float* __restrict__ x,
    const float* __restrict__ qW, const float* __restrict__ qb,
    const float* __restrict__ kW, const float* __restrict__ kb,
    const float* __restrict__ vW, const float* __restrict__ vb,
    const float* __restrict__ sW, const float* __restrict__ sb,
    float* __restrict__ q1, float* __restrict__ kv1,
    float* __restrict__ xr1, int n_nodes) {
  __shared__ __align__(16) float sWt[40 * 128];
  __shared__ float sB[40];
  const int t = threadIdx.x;
  const int g = blockIdx.y;
  const int n0 = blockIdx.x * 512;

  for (int i = t; i < 1280; i += 256) {
    int c = i >> 5, q = i & 31;
    int ch = g * 40 + c;
    float4 w = make_float4(0.f, 0.f, 0.f, 0.f);
    const float* srcr = nullptr;
    if (ch < 50)        srcr = qW + ch * 128;
    else if (ch < 100)  srcr = kW + (ch - 50) * 128;
    else if (ch < 150)  srcr = vW + (ch - 100) * 128;
    else if (ch < 155)  srcr = sW + (ch - 150) * 128;
    if (srcr) w = *(const float4*)(srcr + q * 4);
    *(float4*)&sWt[c * 128 + q * 4] = w;
  }
  if (t < 40) {
    int ch = g * 40 + t;
    float b = 0.f;
    if (ch < 50) b = qb[ch];
    else if (ch < 100) b = kb[ch - 50];
    else if (ch < 150) b = vb[ch - 100];
    else if (ch < 155) b = sb[ch - 150];
    sB[t] = b;
  }
  __syncthreads();

  float accA[40], accB[40];
#pragma unroll
  for (int c = 0; c < 40; ++c) { accA[c] = sB[c]; accB[c] = sB[c]; }
  const int na = n0 + 2 * t, nb = na + 1;
  const bool okA = na < n_nodes, okB = nb < n_nodes;
  const float* xa_p = x + (size_t)(okA ? na : 0) * 128;
  const float* xb_p = x + (size_t)(okB ? nb : 0) * 128;
  const float4* w4 = (const float4*)sWt;

  for (int kc = 0; kc < 128; kc += 8) {
    float4 xa0 = *(const float4*)(xa_p + kc);
    float4 xa1 = *(const float4*)(xa_p + kc + 4);
    float4 xb0 = *(const float4*)(xb_p + kc);
    float4 xb1 = *(const float4*)(xb_p + kc + 4);
    const int base = kc >> 2;
#pragma unroll
    for (int c = 0; c < 40; ++c) {
      float4 w0 = w4[c * 32 + base];
      float4 w1 = w4[c * 32 + base + 1];
      accA[c] = fmaf(w0.x, xa0.x, accA[c]); accA[c] = fmaf(w0.y, xa0.y, accA[c]);
      accA[c] = fmaf(w0.z, xa0.z, accA[c]); accA[c] = fmaf(w0.w, xa0.w, accA[c]);
      accA[c] = fmaf(w1.x, xa1.x, accA[c]); accA[c] = fmaf(w1.y, xa1.y, accA[c]);
      accA[c] = fmaf(w1.z, xa1.z, accA[c]); accA[c] = fmaf(w1.w, xa1.w, accA[c]);
      accB[c] = fmaf(w0.x, xb0.x, accB[c]); accB[c] = fmaf(w0.y, xb0.y, accB[c]);
      accB[c] = fmaf(w0.z, xb0.z, accB[c]); accB[c] = fmaf(w0.w, xb0.w, accB[c]);
      accB[c] = fmaf(w1.x, xb1.x, accB[c]); accB[c] = fmaf(w1.y, xb1.y, accB[c]);
      accB[c] = fmaf(w1.z, xb1.z, accB[c]); accB[c] = fmaf(w1.w, xb1.w, accB[c]);
    }
  }
  if (okA) store40(accA, na, g, q1, kv1, xr1);
  if (okB) store40(accB, nb, g, q1, kv1, xr1);
}

// ---- CSR build -------------------------------------------------------------
__global__ __launch_bounds__(256) void k_hist(const int* __restrict__ ei, int n_edges,
                                              int* __restrict__ cnt) {
  int e = blockIdx.x * 256 + threadIdx.x;
  if (e < n_edges) atomicAdd(&cnt[ei[n_edges + e]], 1);
}

__global__ __launch_bounds__(1024) void k_scan(const int* __restrict__ cnt,
                                               int* __restrict__ rp,
                                               int* __restrict__ cursor, int n) {
  __shared__ int ls[1024];
  int tid = threadIdx.x;
  const int CH = (((n + 1023) / 1024) + 3) & ~3;   // multiple of 4
  int lo = tid * CH, hi = min(lo + CH, n);
  int s = 0;
  if (lo < n) {
    int full = (hi - lo) & ~3;
    const int4* c4 = (const int4*)(cnt + lo);
    for (int i = 0; i < full; i += 4) {
      int4 v = c4[i >> 2];
      s += v.x + v.y + v.z + v.w;
    }
    for (int i = lo + full; i < hi; ++i) s += cnt[i];
  }
  ls[tid] = s;
  __syncthreads();
  for (int off = 1; off < 1024; off <<= 1) {
    int v = (tid >= off) ? ls[tid - off] : 0;
    __syncthreads();
    ls[tid] += v;
    __syncthreads();
  }
  int run = (tid > 0) ? ls[tid - 1] : 0;
  for (int i = lo; i < hi; ++i) {
    rp[i] = run; cursor[i] = run; run += cnt[i];
  }
  if (hi == n && lo < n) rp[n] = run;
}

__global__ __launch_bounds__(256) void k_scatter(const int* __restrict__ ei, int n_edges,
                                                 int* __restrict__ cursor,
                                                 int* __restrict__ seid,
                                                 int* __restrict__ ssrc) {
  int e = blockIdx.x * 256 + threadIdx.x;
  if (e >= n_edges) return;
  int s = ei[e];
  int d = ei[n_edges + e];
  int p = atomicAdd(&cursor[d], 1);
  seid[p] = e;
  ssrc[p] = s;
}

// ---- K-evt: ev1(50)+ev2(10) = attr @ W^T, stored f16 in place over attr ----
__global__ __launch_bounds__(256) void k_evt(
    float* attr, const float* __restrict__ e1W, const float* __restrict__ e2W,
    int n_edges) {
  int e = blockIdx.x * 256 + threadIdx.x;
  if (e >= n_edges) return;
  const float4* ar = (const float4*)(attr + (size_t)e * 32);
  float4 a[8];
#pragma unroll
  for (int j = 0; j < 8; ++j) a[j] = ar[j];
  unsigned int d[30];
#pragma unroll
  for (int c2 = 0; c2 < 30; ++c2) {
    int c0 = 2 * c2, c1 = 2 * c2 + 1;
    const float* w0 = (c0 < 50) ? (e1W + c0 * 32) : (e2W + (c0 - 50) * 32);
    const float* w1 = (c1 < 50) ? (e1W + c1 * 32) : (e2W + (c1 - 50) * 32);
    float acc0 = 0.f, acc1 = 0.f;
#pragma unroll
    for (int j = 0; j < 8; ++j) {
      float4 wa = *(const float4*)(w0 + 4 * j);
      float4 wb = *(const float4*)(w1 + 4 * j);
      acc0 = fmaf(wa.x, a[j].x, acc0); acc0 = fmaf(wa.y, a[j].y, acc0);
      acc0 = fmaf(wa.z, a[j].z, acc0); acc0 = fmaf(wa.w, a[j].w, acc0);
      acc1 = fmaf(wb.x, a[j].x, acc1); acc1 = fmaf(wb.y, a[j].y, acc1);
      acc1 = fmaf(wb.z, a[j].z, acc1); acc1 = fmaf(wb.w, a[j].w, acc1);
    }
    union { _Float16 h[2]; unsigned int u; } p;
    p.h[0] = (_Float16)acc0; p.h[1] = (_Float16)acc1;
    d[c2] = p.u;
  }
  unsigned int* row = (unsigned int*)(attr + (size_t)e * 32);
#pragma unroll
  for (int k = 0; k < 7; ++k)
    *(uint4*)(row + 4 * k) = make_uint4(d[4 * k], d[4 * k + 1], d[4 * k + 2], d[4 * k + 3]);
  *(uint2*)(row + 28) = make_uint2(d[28], d[29]);
}

// ---- K-conv1: persistent wave per dst node; 2-edge unrolled ----------------
__global__ __launch_bounds__(256) void k_conv1(
    const int* __restrict__ rp, const int* __restrict__ seid,
    const int* __restrict__ ssrc, const float* __restrict__ attr,
    const float* __restrict__ q1, const float* __restrict__ kv1,
    const float* __restrict__ xr1,
    const float* __restrict__ bW, float* __restrict__ h1, int n_nodes) {
  const int lane = threadIdx.x & 63;
  const int wid = (blockIdx.x * 256 + threadIdx.x) >> 6;
  const int nw = gridDim.x * 4;
  const int wr = (lane < 50) ? lane : 0;
  const int g0 = (wr / 5) * 5;
  const int cp = lane % 5;
  const unsigned short* evr = (const unsigned short*)attr;

  for (int n = wid; n < n_nodes; n += nw) {
    const int p0 = rp[n], deg = rp[n + 1] - p0;
    const float qc = q1[(size_t)n * 52 + wr];
    int eL = 0, sL = 0;
    if (lane < deg) { eL = seid[p0 + lane]; sL = ssrc[p0 + lane]; }
    float accN0 = 0.f, accD0 = 0.f, accN1 = 0.f, accD1 = 0.f;
    int i = 0;
    for (; i + 2 <= deg; i += 2) {
      int e0, s0, e1, s1;
      if (i + 1 < 64) {
        e0 = __shfl(eL, i);     s0 = __shfl(sL, i);
        e1 = __shfl(eL, i + 1); s1 = __shfl(sL, i + 1);
      } else {
        e0 = (i < 64) ? __shfl(eL, i) : seid[p0 + i];
        s0 = (i < 64) ? __shfl(sL, i) : ssrc[p0 + i];
        e1 = seid[p0 + i + 1];  s1 = ssrc[p0 + i + 1];
      }
      float ev0 = f16_to_f32(evr[(size_t)e0 * 64 + wr]);
      float ev1 = f16_to_f32(evr[(size_t)e1 * 64 + wr]);
      float2 kva = *(const float2*)(kv1 + (size_t)s0 * 104 + 2 * wr);
      float2 kvb = *(const float2*)(kv1 + (size_t)s1 * 104 + 2 * wr);
      float t0 = qc * (kva.x + ev0);
      float t1 = qc * (kvb.x + ev1);
      float al0 = __shfl(t0, g0) + __shfl(t0, g0 + 1) + __shfl(t0, g0 + 2)
                + __shfl(t0, g0 + 3) + __shfl(t0, g0 + 4);
      float al1 = __shfl(t1, g0) + __shfl(t1, g0 + 1) + __shfl(t1, g0 + 2)
                + __shfl(t1, g0 + 3) + __shfl(t1, g0 + 4);
      float ex0 = __expf(al0 * INV_SQRT5);
      float ex1 = __expf(al1 * INV_SQRT5);
      accD0 += ex0; accN0 = fmaf(kva.y + ev0, ex0, accN0);
      accD1 += ex1; accN1 = fmaf(kvb.y + ev1, ex1, accN1);
    }
    if (i < deg) {
      int e = (i < 64) ? __shfl(eL, i) : seid[p0 + i];
      int s = (i < 64) ? __shfl(sL, i) : ssrc[p0 + i];
      float ev = f16_to_f32(evr[(size_t)e * 64 + wr]);
      float2 kv = *(const float2*)(kv1 + (size_t)s * 104 + 2 * wr);
      float t = qc * (kv.x + ev);
      float al = __shfl(t, g0) + __shfl(t, g0 + 1) + __shfl(t, g0 + 2)
               + __shfl(t, g0 + 3) + __shfl(t, g0 + 4);
      float ex = __expf(al * INV_SQRT5);
      accD0 += ex; accN0 = fmaf(kv.y + ev, ex, accN0);
    }
    float accN = accN0 + accN1, accD = accD0 + accD1;
    float r = (accD > 0.f) ? accN / accD : 0.f;
    if (lane >= 50) r = 0.f;
    float o = 0.f;
#pragma unroll
    for (int h = 0; h < 10; ++h) o += __shfl(r, cp + 5 * h);
    o *= 0.1f;
    float xr = xr1[(size_t)n * 8 + cp];
    float tb = bW[cp] * o + bW[5 + cp] * xr + bW[10 + cp] * (o - xr);
    float sb = 0.f;
#pragma unroll
    for (int j = 0; j < 5; ++j) sb += __shfl(tb, j);
    float beta = 1.f / (1.f + __expf(-sb));
    if (lane < 5) h1[(size_t)n * 8 + lane] = beta * xr + (1.f - beta) * o;
  }
}

// ---- GraphNorm stats, single pass (sum, sumsq, count) ----------------------
__global__ __launch_bounds__(256) void k_stats(
    const float* __restrict__ h1, const int* __restrict__ batch,
    float* __restrict__ gsum, float* __restrict__ gsq,
    float* __restrict__ gcnt, int n_nodes) {
  int n = blockIdx.x * 256 + threadIdx.x;
  bool act = n < n_nodes;
  int g = act ? batch[n] : 0;
  float v[5], s2[5], one = act ? 1.f : 0.f;
#pragma unroll
  for (int c = 0; c < 5; ++c) {
    v[c] = act ? h1[(size_t)n * 8 + c] : 0.f;
    s2[c] = v[c] * v[c];
  }
  int g0 = __shfl(g, 0);
  bool uni = __all((!act) || (g == g0));
  if (uni) {
#pragma unroll
    for (int off = 32; off; off >>= 1) {
#pragma unroll
      for (int c = 0; c < 5; ++c) {
        v[c] += __shfl_down(v[c], off);
        s2[c] += __shfl_down(s2[c], off);
      }
      one += __shfl_down(one, off);
    }
    if ((threadIdx.x & 63) == 0) {
#pragma unroll
      for (int c = 0; c < 5; ++c) {
        atomicAdd(&gsum[g0 * 8 + c], v[c]);
        atomicAdd(&gsq[g0 * 8 + c], s2[c]);
      }
      atomicAdd(&gcnt[g0], one);
    }
  } else if (act) {
#pragma unroll
    for (int c = 0; c < 5; ++c) {
      atomicAdd(&gsum[g * 8 + c], v[c]);
      atomicAdd(&gsq[g * 8 + c], s2[c]);
    }
    atomicAdd(&gcnt[g], 1.f);
  }
}

// ---- apply norm + relu + q2/kv2/xr2 ----------------------------------------
__global__ __launch_bounds__(256) void k_apply(
    const float* __restrict__ h1, const int* __restrict__ batch,
    const float* __restrict__ gsum, const float* __restrict__ gsq,
    const float* __restrict__ gcnt,
    const float* __restrict__ gnw, const float* __restrict__ gnb,
    const float* __restrict__ gnms,
    const float* __restrict__ q2W, const float* __restrict__ q2b,
    const float* __restrict__ k2W, const float* __restrict__ k2b,
    const float* __restrict__ v2W, const float* __restrict__ v2b,
    const float* __restrict__ s2W, const float* __restrict__ s2b,
    float* __restrict__ q2, float* __restrict__ kv2,
    float* __restrict__ xr2, int n_nodes) {
  int n = blockIdx.x * 256 + threadIdx.x;
  if (n >= n_nodes) return;
  int g = batch[n];
  float rc = 1.f / fmaxf(gcnt[g], 1.f);
  float r[5];
#pragma unroll
  for (int c = 0; c < 5; ++c) {
    float ms = gnms[c];
    float mean = gsum[g * 8 + c] * rc;
    float var = gsq[g * 8 + c] * rc - mean * mean * ms * (2.f - ms);
    var = fmaxf(var, 0.f);
    float o = h1[(size_t)n * 8 + c] - mean * ms;
    float y = gnw[c] * o * rsqrtf(var + EPS) + gnb[c];
    r[c] = fmaxf(y, 0.f);
  }
#pragma unroll
  for (int h = 0; h < 10; ++h) {
    float aq = q2b[h], ak = k2b[h], av = v2b[h];
#pragma unroll
    for (int i = 0; i < 5; ++i) {
      aq = fmaf(r[i], q2W[h * 5 + i], aq);
      ak = fmaf(r[i], k2W[h * 5 + i], ak);
      av = fmaf(r[i], v2W[h * 5 + i], av);
    }
    q2[(size_t)n * 12 + h] = aq;
    kv2[(size_t)n * 24 + 2 * h]     = ak;
    kv2[(size_t)n * 24 + 2 * h + 1] = av;
  }
  float s = s2b[0];
#pragma unroll
  for (int i = 0; i < 5; ++i) s = fmaf(r[i], s2W[i], s);
  xr2[n] = s;
}

// ---- K-conv2: persistent wave per node, 6 edges x 10 heads -----------------
__global__ __launch_bounds__(256) void k_conv2(
    const int* __restrict__ rp, const int* __restrict__ seid,
    const int* __restrict__ ssrc, const float* __restrict__ attr,
    const float* __restrict__ q2, const float* __restrict__ kv2,
    const float* __restrict__ xr2,
    const float* __restrict__ bW, float* __restrict__ out, int n_nodes) {
  const int lane = threadIdx.x & 63;
  const int wid = (blockIdx.x * 256 + threadIdx.x) >> 6;
  const int nw = gridDim.x * 4;
  const int slot = lane / 10, h = lane - slot * 10;
  const bool active = slot < 6;
  const unsigned short* evr = (const unsigned short*)attr;

  for (int n = wid; n < n_nodes; n += nw) {
    int p0 = rp[n], deg = rp[n + 1] - p0;
    float qh = q2[(size_t)n * 12 + h];
    int eL = 0, sL = 0;
    if (lane < deg) { eL = seid[p0 + lane]; sL = ssrc[p0 + lane]; }
    float accN = 0.f, accD = 0.f;
    int nit = (deg + 5) / 6;
    for (int t = 0; t < nit; ++t) {
      int i = t * 6 + slot;
      bool val = active && (i < deg);
      int e = 0, s = 0;
      if (i < 64) { e = __shfl(eL, i); s = __shfl(sL, i); }
      else if (val) { e = seid[p0 + i]; s = ssrc[p0 + i]; }
      float evv = 0.f; float2 kv = make_float2(0.f, 0.f);
      if (val) {
        evv = f16_to_f32(evr[(size_t)e * 64 + 50 + h]);
        kv = *(const float2*)(kv2 + (size_t)s * 24 + 2 * h);
      }
      float exv = val ? __expf(qh * (kv.x + evv)) : 0.f;
      accD += exv;
      accN = fmaf(kv.y + evv, exv, accN);
    }
    float D = 0.f, Nn = 0.f;
#pragma unroll
    for (int i2 = 0; i2 < 6; ++i2) {
      D  += __shfl(accD, h + 10 * i2);
      Nn += __shfl(accN, h + 10 * i2);
    }
    float r = (D > 0.f) ? Nn / D : 0.f;
    float o = 0.f;
#pragma unroll
    for (int j = 0; j < 10; ++j) o += __shfl(r, j);
    o *= 0.1f;
    float xr = xr2[n];
    float sbv = bW[0] * o + bW[1] * xr + bW[2] * (o - xr);
    float beta = 1.f / (1.f + __expf(-sbv));
    float y = beta * xr + (1.f - beta) * o;
    if (lane == 0) out[n] = 1.f / (1.f + __expf(-y));
  }
}

// ---------------------------------------------------------------------------
extern "C" void kernel_launch(void* const* d_in, const int* in_sizes, int n_in,
                              void* d_out, int out_size, void* d_ws, size_t ws_size,
                              hipStream_t stream) {
  const float* x    = (const float*)d_in[0];
  float*       attr = (float*)d_in[1];          // overwritten in-place by k_evt
  const int*   ei   = (const int*)d_in[2];
  const int*   batch= (const int*)d_in[3];
  const float* q1W = (const float*)d_in[4];  const float* q1b = (const float*)d_in[5];
  const float* k1W = (const float*)d_in[6];  const float* k1b = (const float*)d_in[7];
  const float* v1W = (const float*)d_in[8];  const float* v1b = (const float*)d_in[9];
  const float* e1W = (const float*)d_in[10];
  const float* s1W = (const float*)d_in[11]; const float* s1b = (const float*)d_in[12];
  const float* b1W = (const float*)d_in[13];
  const float* gnW = (const float*)d_in[14]; const float* gnb = (const float*)d_in[15];
  const float* gnms= (const float*)d_in[16];
  const float* q2W = (const float*)d_in[17]; const float* q2b = (const float*)d_in[18];
  const float* k2W = (const float*)d_in[19]; const float* k2b = (const float*)d_in[20];
  const float* v2W = (const float*)d_in[21]; const float* v2b = (const float*)d_in[22];
  const float* e2W = (const float*)d_in[23];
  const float* s2W = (const float*)d_in[24]; const float* s2b = (const float*)d_in[25];
  const float* b2W = (const float*)d_in[26];

  const int n_nodes = in_sizes[0] / 128;
  const int n_edges = in_sizes[2] / 2;
  float* ws = (float*)d_ws;
  const size_t nn = (size_t)n_nodes;
  const size_t ne = (size_t)n_edges;

  // workspace layout (float units)
  const size_t oQ1  = 0;              // 52*nn
  const size_t oKV1 = 52 * nn;        // 104*nn (k/v interleaved)
  const size_t oXR1 = 156 * nn;       // 8*nn
  const size_t oH1  = 164 * nn;       // 8*nn
  const size_t oQ2  = 172 * nn;       // 12*nn
  const size_t oKV2 = 184 * nn;       // 24*nn
  const size_t oXR2 = 208 * nn;       // nn
  const size_t oSTAT= 209 * nn;       // 1088 (gsum 512 | gsq 512 | gcnt 64)
  const size_t oCNT = oSTAT + 1088;   // nn ints   (contiguous with STAT: 1 memset)
  const size_t oRP  = oCNT + nn;      // nn+1 ints
  const size_t oCUR = oRP + nn + 1;   // nn ints
  const size_t oSEID= oCUR + nn;      // ne ints
  const size_t oSSRC= oSEID + ne;     // ne ints
  // total ~= 212*nn + 2*ne + 1.1K floats ~= 98 MB

  int* cnt    = (int*)(ws + oCNT);
  int* rp     = (int*)(ws + oRP);
  int* cursor = (int*)(ws + oCUR);
  int* seid   = (int*)(ws + oSEID);
  int* ssrc   = (int*)(ws + oSSRC);
  float* gsum = ws + oSTAT;
  float* gsq  = ws + oSTAT + 512;
  float* gcnt = ws + oSTAT + 1024;

  const int nb_nodes = (n_nodes + 255) / 256;
  const int nb_edges = (n_edges + 255) / 256;
  dim3 gq((n_nodes + 511) / 512, 4);
  const int nb_pers = 2048;  // persistent-wave grid for conv kernels

  // one memset covers stats (1088 f) + cnt (nn ints)
  hipMemsetAsync(ws + oSTAT, 0, (1088 + nn) * sizeof(float), stream);

  k_hist<<<nb_edges, 256, 0, stream>>>(ei, n_edges, cnt);
  k_scan<<<1, 1024, 0, stream>>>(cnt, rp, cursor, n_nodes);
  k_scatter<<<nb_edges, 256, 0, stream>>>(ei, n_edges, cursor, seid, ssrc);

  k_qkvs1<<<gq, 256, 0, stream>>>(x, q1W, q1b, k1W, k1b, v1W, v1b, s1W, s1b,
                                  ws + oQ1, ws + oKV1, ws + oXR1, n_nodes);
  k_evt<<<nb_edges, 256, 0, stream>>>(attr, e1W, e2W, n_edges);

  k_conv1<<<nb_pers, 256, 0, stream>>>(rp, seid, ssrc, attr,
                                       ws + oQ1, ws + oKV1, ws + oXR1,
                                       b1W, ws + oH1, n_nodes);
  k_stats<<<nb_nodes, 256, 0, stream>>>(ws + oH1, batch, gsum, gsq, gcnt, n_nodes);
  k_apply<<<nb_nodes, 256, 0, stream>>>(ws + oH1, batch, gsum, gsq, gcnt,
                                        gnW, gnb, gnms,
                                        q2W, q2b, k2W, k2b, v2W, v2b, s2W, s2b,
                                        ws + oQ2, ws + oKV2, ws + oXR2, n_nodes);
  k_conv2<<<nb_pers, 256, 0, stream>>>(rp, seid, ssrc, attr,
                                       ws + oQ2, ws + oKV2, ws + oXR2,
                                       b2W, (float*)d_out, n_nodes);
}

// Round 3
// 1064.250 us; speedup vs baseline: 1.2232x; 1.1727x over previous
//
#include <hip/hip_runtime.h>
#include <math.h>

// ---------------------------------------------------------------------------
// mTransformerConv: 2x TransformerConv (H=10, c=5 then c=1) + GraphNorm + relu
// N=100000, E=1600000, D_NODE=128, D_EDGE=32, G=64.
// Round 9: k_scan (single-block serial scan, 206us @ 0.14% occupancy) replaced
// by a 3-phase parallel scan: per-block sums -> tiny top-level exclusive scan
// -> per-block scan-out with int4 stores of rp+cursor (~8us total).
// oCUR padded +4 floats so cursor int4 stores are 16B-aligned.
// ---------------------------------------------------------------------------

#define EPS 1e-5f
#define INV_SQRT5 0.44721359549995794f

__device__ __forceinline__ float f16_to_f32(unsigned short u) {
  union { unsigned short us; _Float16 h; } cv; cv.us = u;
  return (float)cv.h;
}

__device__ __forceinline__ void store40(const float (&acc)[40], int n, int g,
                                        float* __restrict__ q1, float* __restrict__ kv1,
                                        float* __restrict__ xr1) {
#pragma unroll
  for (int c = 0; c < 40; ++c) {
    int ch = g * 40 + c;
    if (ch < 50)        q1[(size_t)n * 52 + ch] = acc[c];
    else if (ch < 100)  kv1[(size_t)n * 104 + 2 * (ch - 50)] = acc[c];
    else if (ch < 150)  kv1[(size_t)n * 104 + 2 * (ch - 100) + 1] = acc[c];
    else if (ch < 155)  xr1[(size_t)n * 8 + (ch - 150)] = acc[c];
  }
}

// ---- K1: q1/kv1/xr1 GEMM. 512 nodes x 40 ch per block ----------------------
__global__ __launch_bounds__(256, 4) void k_qkvs1(
    const float* __restrict__ x,
    const float* __restrict__ qW, const float* __restrict__ qb,
    const float* __restrict__ kW, const float* __restrict__ kb,
    const float* __restrict__ vW, const float* __restrict__ vb,
    const float* __restrict__ sW, const float* __restrict__ sb,
    float* __restrict__ q1, float* __restrict__ kv1,
    float* __restrict__ xr1, int n_nodes) {
  __shared__ __align__(16) float sWt[40 * 128];
  __shared__ float sB[40];
  const int t = threadIdx.x;
  const int g = blockIdx.y;
  const int n0 = blockIdx.x * 512;

  for (int i = t; i < 1280; i += 256) {
    int c = i >> 5, q = i & 31;
    int ch = g * 40 + c;
    float4 w = make_float4(0.f, 0.f, 0.f, 0.f);
    const float* srcr = nullptr;
    if (ch < 50)        srcr = qW + ch * 128;
    else if (ch < 100)  srcr = kW + (ch - 50) * 128;
    else if (ch < 150)  srcr = vW + (ch - 100) * 128;
    else if (ch < 155)  srcr = sW + (ch - 150) * 128;
    if (srcr) w = *(const float4*)(srcr + q * 4);
    *(float4*)&sWt[c * 128 + q * 4] = w;
  }
  if (t < 40) {
    int ch = g * 40 + t;
    float b = 0.f;
    if (ch < 50) b = qb[ch];
    else if (ch < 100) b = kb[ch - 50];
    else if (ch < 150) b = vb[ch - 100];
    else if (ch < 155) b = sb[ch - 150];
    sB[t] = b;
  }
  __syncthreads();

  float accA[40], accB[40];
#pragma unroll
  for (int c = 0; c < 40; ++c) { accA[c] = sB[c]; accB[c] = sB[c]; }
  const int na = n0 + 2 * t, nb = na + 1;
  const bool okA = na < n_nodes, okB = nb < n_nodes;
  const float* xa_p = x + (size_t)(okA ? na : 0) * 128;
  const float* xb_p = x + (size_t)(okB ? nb : 0) * 128;
  const float4* w4 = (const float4*)sWt;

  for (int kc = 0; kc < 128; kc += 8) {
    float4 xa0 = *(const float4*)(xa_p + kc);
    float4 xa1 = *(const float4*)(xa_p + kc + 4);
    float4 xb0 = *(const float4*)(xb_p + kc);
    float4 xb1 = *(const float4*)(xb_p + kc + 4);
    const int base = kc >> 2;
#pragma unroll
    for (int c = 0; c < 40; ++c) {
      float4 w0 = w4[c * 32 + base];
      float4 w1 = w4[c * 32 + base + 1];
      accA[c] = fmaf(w0.x, xa0.x, accA[c]); accA[c] = fmaf(w0.y, xa0.y, accA[c]);
      accA[c] = fmaf(w0.z, xa0.z, accA[c]); accA[c] = fmaf(w0.w, xa0.w, accA[c]);
      accA[c] = fmaf(w1.x, xa1.x, accA[c]); accA[c] = fmaf(w1.y, xa1.y, accA[c]);
      accA[c] = fmaf(w1.z, xa1.z, accA[c]); accA[c] = fmaf(w1.w, xa1.w, accA[c]);
      accB[c] = fmaf(w0.x, xb0.x, accB[c]); accB[c] = fmaf(w0.y, xb0.y, accB[c]);
      accB[c] = fmaf(w0.z, xb0.z, accB[c]); accB[c] = fmaf(w0.w, xb0.w, accB[c]);
      accB[c] = fmaf(w1.x, xb1.x, accB[c]); accB[c] = fmaf(w1.y, xb1.y, accB[c]);
      accB[c] = fmaf(w1.w, xb1.w, accB[c]); accB[c] = fmaf(w1.z, xb1.z, accB[c]);
    }
  }
  if (okA) store40(accA, na, g, q1, kv1, xr1);
  if (okB) store40(accB, nb, g, q1, kv1, xr1);
}

// ---- CSR build -------------------------------------------------------------
__global__ __launch_bounds__(256) void k_hist(const int* __restrict__ ei, int n_edges,
                                              int* __restrict__ cnt) {
  int e = blockIdx.x * 256 + threadIdx.x;
  if (e < n_edges) atomicAdd(&cnt[ei[n_edges + e]], 1);
}

// ---- 3-phase parallel exclusive scan (1024 elems/block) --------------------
__global__ __launch_bounds__(256) void k_scansum(const int* __restrict__ cnt,
                                                 int* __restrict__ bsum, int n) {
  int base = blockIdx.x * 1024 + threadIdx.x * 4;
  int s = 0;
  if (base + 3 < n) {
    int4 v = *(const int4*)(cnt + base);
    s = v.x + v.y + v.z + v.w;
  } else {
    for (int i = base; i < n && i < base + 4; ++i) s += cnt[i];
  }
#pragma unroll
  for (int off = 32; off; off >>= 1) s += __shfl_down(s, off);
  __shared__ int wsum[4];
  if ((threadIdx.x & 63) == 0) wsum[threadIdx.x >> 6] = s;
  __syncthreads();
  if (threadIdx.x == 0) bsum[blockIdx.x] = wsum[0] + wsum[1] + wsum[2] + wsum[3];
}

__global__ __launch_bounds__(256) void k_scantop(int* __restrict__ bsum, int nb) {
  // exclusive scan in place; nb <= 256
  __shared__ int ls[256];
  int tid = threadIdx.x;
  int v = (tid < nb) ? bsum[tid] : 0;
  ls[tid] = v;
  __syncthreads();
  for (int off = 1; off < 256; off <<= 1) {
    int t = (tid >= off) ? ls[tid - off] : 0;
    __syncthreads();
    ls[tid] += t;
    __syncthreads();
  }
  if (tid < nb) bsum[tid] = ls[tid] - v;
}

__global__ __launch_bounds__(256) void k_scanout(const int* __restrict__ cnt,
                                                 const int* __restrict__ bsum,
                                                 int* __restrict__ rp,
                                                 int* __restrict__ cursor, int n) {
  const int tid = threadIdx.x;
  const int lane = tid & 63;
  const int w = tid >> 6;
  int base = blockIdx.x * 1024 + tid * 4;
  int c0 = 0, c1 = 0, c2 = 0, c3 = 0;
  if (base + 3 < n) {
    int4 v = *(const int4*)(cnt + base);
    c0 = v.x; c1 = v.y; c2 = v.z; c3 = v.w;
  } else if (base < n) {
    c0 = cnt[base];
    if (base + 1 < n) c1 = cnt[base + 1];
    if (base + 2 < n) c2 = cnt[base + 2];
    if (base + 3 < n) c3 = cnt[base + 3];
  }
  int s = c0 + c1 + c2 + c3;
  // inclusive wave scan of s
  int incl = s;
#pragma unroll
  for (int off = 1; off < 64; off <<= 1) {
    int t = __shfl_up(incl, off);
    if (lane >= off) incl += t;
  }
  __shared__ int wsum[4];
  if (lane == 63) wsum[w] = incl;
  __syncthreads();
  int woff = 0;
#pragma unroll
  for (int j = 0; j < 3; ++j) if (j < w) woff += wsum[j];
  int excl = bsum[blockIdx.x] + woff + (incl - s);
  int4 o;
  o.x = excl; o.y = o.x + c0; o.z = o.y + c1; o.w = o.z + c2;
  if (base + 3 < n) {
    *(int4*)(rp + base) = o;
    *(int4*)(cursor + base) = o;
  } else if (base < n) {
    rp[base] = o.x; cursor[base] = o.x;
    if (base + 1 < n) { rp[base + 1] = o.y; cursor[base + 1] = o.y; }
    if (base + 2 < n) { rp[base + 2] = o.z; cursor[base + 2] = o.z; }
  }
  if (base < n && base + 4 >= n) rp[n] = excl + s;  // total (last thread only)
}

__global__ __launch_bounds__(256) void k_scatter(const int* __restrict__ ei, int n_edges,
                                                 int* __restrict__ cursor,
                                                 int* __restrict__ seid,
                                                 int* __restrict__ ssrc) {
  int e = blockIdx.x * 256 + threadIdx.x;
  if (e >= n_edges) return;
  int s = ei[e];
  int d = ei[n_edges + e];
  int p = atomicAdd(&cursor[d], 1);
  seid[p] = e;
  ssrc[p] = s;
}

// ---- K-evt: ev1(50)+ev2(10) = attr @ W^T, stored f16 in place over attr ----
__global__ __launch_bounds__(256) void k_evt(
    float* attr, const float* __restrict__ e1W, const float* __restrict__ e2W,
    int n_edges) {
  int e = blockIdx.x * 256 + threadIdx.x;
  if (e >= n_edges) return;
  const float4* ar = (const float4*)(attr + (size_t)e * 32);
  float4 a[8];
#pragma unroll
  for (int j = 0; j < 8; ++j) a[j] = ar[j];
  unsigned int d[30];
#pragma unroll
  for (int c2 = 0; c2 < 30; ++c2) {
    int c0 = 2 * c2, c1 = 2 * c2 + 1;
    const float* w0 = (c0 < 50) ? (e1W + c0 * 32) : (e2W + (c0 - 50) * 32);
    const float* w1 = (c1 < 50) ? (e1W + c1 * 32) : (e2W + (c1 - 50) * 32);
    float acc0 = 0.f, acc1 = 0.f;
#pragma unroll
    for (int j = 0; j < 8; ++j) {
      float4 wa = *(const float4*)(w0 + 4 * j);
      float4 wb = *(const float4*)(w1 + 4 * j);
      acc0 = fmaf(wa.x, a[j].x, acc0); acc0 = fmaf(wa.y, a[j].y, acc0);
      acc0 = fmaf(wa.z, a[j].z, acc0); acc0 = fmaf(wa.w, a[j].w, acc0);
      acc1 = fmaf(wb.x, a[j].x, acc1); acc1 = fmaf(wb.y, a[j].y, acc1);
      acc1 = fmaf(wb.z, a[j].z, acc1); acc1 = fmaf(wb.w, a[j].w, acc1);
    }
    union { _Float16 h[2]; unsigned int u; } p;
    p.h[0] = (_Float16)acc0; p.h[1] = (_Float16)acc1;
    d[c2] = p.u;
  }
  unsigned int* row = (unsigned int*)(attr + (size_t)e * 32);
#pragma unroll
  for (int k = 0; k < 7; ++k)
    *(uint4*)(row + 4 * k) = make_uint4(d[4 * k], d[4 * k + 1], d[4 * k + 2], d[4 * k + 3]);
  *(uint2*)(row + 28) = make_uint2(d[28], d[29]);
}

// ---- K-conv1: persistent wave per dst node; 2-edge unrolled ----------------
__global__ __launch_bounds__(256) void k_conv1(
    const int* __restrict__ rp, const int* __restrict__ seid,
    const int* __restrict__ ssrc, const float* __restrict__ attr,
    const float* __restrict__ q1, const float* __restrict__ kv1,
    const float* __restrict__ xr1,
    const float* __restrict__ bW, float* __restrict__ h1, int n_nodes) {
  const int lane = threadIdx.x & 63;
  const int wid = (blockIdx.x * 256 + threadIdx.x) >> 6;
  const int nw = gridDim.x * 4;
  const int wr = (lane < 50) ? lane : 0;
  const int g0 = (wr / 5) * 5;
  const int cp = lane % 5;
  const unsigned short* evr = (const unsigned short*)attr;

  for (int n = wid; n < n_nodes; n += nw) {
    const int p0 = rp[n], deg = rp[n + 1] - p0;
    const float qc = q1[(size_t)n * 52 + wr];
    int eL = 0, sL = 0;
    if (lane < deg) { eL = seid[p0 + lane]; sL = ssrc[p0 + lane]; }
    float accN0 = 0.f, accD0 = 0.f, accN1 = 0.f, accD1 = 0.f;
    int i = 0;
    for (; i + 2 <= deg; i += 2) {
      int e0, s0, e1, s1;
      if (i + 1 < 64) {
        e0 = __shfl(eL, i);     s0 = __shfl(sL, i);
        e1 = __shfl(eL, i + 1); s1 = __shfl(sL, i + 1);
      } else {
        e0 = (i < 64) ? __shfl(eL, i) : seid[p0 + i];
        s0 = (i < 64) ? __shfl(sL, i) : ssrc[p0 + i];
        e1 = seid[p0 + i + 1];  s1 = ssrc[p0 + i + 1];
      }
      float ev0 = f16_to_f32(evr[(size_t)e0 * 64 + wr]);
      float ev1 = f16_to_f32(evr[(size_t)e1 * 64 + wr]);
      float2 kva = *(const float2*)(kv1 + (size_t)s0 * 104 + 2 * wr);
      float2 kvb = *(const float2*)(kv1 + (size_t)s1 * 104 + 2 * wr);
      float t0 = qc * (kva.x + ev0);
      float t1 = qc * (kvb.x + ev1);
      float al0 = __shfl(t0, g0) + __shfl(t0, g0 + 1) + __shfl(t0, g0 + 2)
                + __shfl(t0, g0 + 3) + __shfl(t0, g0 + 4);
      float al1 = __shfl(t1, g0) + __shfl(t1, g0 + 1) + __shfl(t1, g0 + 2)
                + __shfl(t1, g0 + 3) + __shfl(t1, g0 + 4);
      float ex0 = __expf(al0 * INV_SQRT5);
      float ex1 = __expf(al1 * INV_SQRT5);
      accD0 += ex0; accN0 = fmaf(kva.y + ev0, ex0, accN0);
      accD1 += ex1; accN1 = fmaf(kvb.y + ev1, ex1, accN1);
    }
    if (i < deg) {
      int e = (i < 64) ? __shfl(eL, i) : seid[p0 + i];
      int s = (i < 64) ? __shfl(sL, i) : ssrc[p0 + i];
      float ev = f16_to_f32(evr[(size_t)e * 64 + wr]);
      float2 kv = *(const float2*)(kv1 + (size_t)s * 104 + 2 * wr);
      float t = qc * (kv.x + ev);
      float al = __shfl(t, g0) + __shfl(t, g0 + 1) + __shfl(t, g0 + 2)
               + __shfl(t, g0 + 3) + __shfl(t, g0 + 4);
      float ex = __expf(al * INV_SQRT5);
      accD0 += ex; accN0 = fmaf(kv.y + ev, ex, accN0);
    }
    float accN = accN0 + accN1, accD = accD0 + accD1;
    float r = (accD > 0.f) ? accN / accD : 0.f;
    if (lane >= 50) r = 0.f;
    float o = 0.f;
#pragma unroll
    for (int h = 0; h < 10; ++h) o += __shfl(r, cp + 5 * h);
    o *= 0.1f;
    float xr = xr1[(size_t)n * 8 + cp];
    float tb = bW[cp] * o + bW[5 + cp] * xr + bW[10 + cp] * (o - xr);
    float sb = 0.f;
#pragma unroll
    for (int j = 0; j < 5; ++j) sb += __shfl(tb, j);
    float beta = 1.f / (1.f + __expf(-sb));
    if (lane < 5) h1[(size_t)n * 8 + lane] = beta * xr + (1.f - beta) * o;
  }
}

// ---- GraphNorm stats, single pass (sum, sumsq, count) ----------------------
__global__ __launch_bounds__(256) void k_stats(
    const float* __restrict__ h1, const int* __restrict__ batch,
    float* __restrict__ gsum, float* __restrict__ gsq,
    float* __restrict__ gcnt, int n_nodes) {
  int n = blockIdx.x * 256 + threadIdx.x;
  bool act = n < n_nodes;
  int g = act ? batch[n] : 0;
  float v[5], s2[5], one = act ? 1.f : 0.f;
#pragma unroll
  for (int c = 0; c < 5; ++c) {
    v[c] = act ? h1[(size_t)n * 8 + c] : 0.f;
    s2[c] = v[c] * v[c];
  }
  int g0 = __shfl(g, 0);
  bool uni = __all((!act) || (g == g0));
  if (uni) {
#pragma unroll
    for (int off = 32; off; off >>= 1) {
#pragma unroll
      for (int c = 0; c < 5; ++c) {
        v[c] += __shfl_down(v[c], off);
        s2[c] += __shfl_down(s2[c], off);
      }
      one += __shfl_down(one, off);
    }
    if ((threadIdx.x & 63) == 0) {
#pragma unroll
      for (int c = 0; c < 5; ++c) {
        atomicAdd(&gsum[g0 * 8 + c], v[c]);
        atomicAdd(&gsq[g0 * 8 + c], s2[c]);
      }
      atomicAdd(&gcnt[g0], one);
    }
  } else if (act) {
#pragma unroll
    for (int c = 0; c < 5; ++c) {
      atomicAdd(&gsum[g * 8 + c], v[c]);
      atomicAdd(&gsq[g * 8 + c], s2[c]);
    }
    atomicAdd(&gcnt[g], 1.f);
  }
}

// ---- apply norm + relu + q2/kv2/xr2 ----------------------------------------
__global__ __launch_bounds__(256) void k_apply(
    const float* __restrict__ h1, const int* __restrict__ batch,
    const float* __restrict__ gsum, const float* __restrict__ gsq,
    const float* __restrict__ gcnt,
    const float* __restrict__ gnw, const float* __restrict__ gnb,
    const float* __restrict__ gnms,
    const float* __restrict__ q2W, const float* __restrict__ q2b,
    const float* __restrict__ k2W, const float* __restrict__ k2b,
    const float* __restrict__ v2W, const float* __restrict__ v2b,
    const float* __restrict__ s2W, const float* __restrict__ s2b,
    float* __restrict__ q2, float* __restrict__ kv2,
    float* __restrict__ xr2, int n_nodes) {
  int n = blockIdx.x * 256 + threadIdx.x;
  if (n >= n_nodes) return;
  int g = batch[n];
  float rc = 1.f / fmaxf(gcnt[g], 1.f);
  float r[5];
#pragma unroll
  for (int c = 0; c < 5; ++c) {
    float ms = gnms[c];
    float mean = gsum[g * 8 + c] * rc;
    float var = gsq[g * 8 + c] * rc - mean * mean * ms * (2.f - ms);
    var = fmaxf(var, 0.f);
    float o = h1[(size_t)n * 8 + c] - mean * ms;
    float y = gnw[c] * o * rsqrtf(var + EPS) + gnb[c];
    r[c] = fmaxf(y, 0.f);
  }
#pragma unroll
  for (int h = 0; h < 10; ++h) {
    float aq = q2b[h], ak = k2b[h], av = v2b[h];
#pragma unroll
    for (int i = 0; i < 5; ++i) {
      aq = fmaf(r[i], q2W[h * 5 + i], aq);
      ak = fmaf(r[i], k2W[h * 5 + i], ak);
      av = fmaf(r[i], v2W[h * 5 + i], av);
    }
    q2[(size_t)n * 12 + h] = aq;
    kv2[(size_t)n * 24 + 2 * h]     = ak;
    kv2[(size_t)n * 24 + 2 * h + 1] = av;
  }
  float s = s2b[0];
#pragma unroll
  for (int i = 0; i < 5; ++i) s = fmaf(r[i], s2W[i], s);
  xr2[n] = s;
}

// ---- K-conv2: persistent wave per node, 6 edges x 10 heads -----------------
__global__ __launch_bounds__(256) void k_conv2(
    const int* __restrict__ rp, const int* __restrict__ seid,
    const int* __restrict__ ssrc, const float* __restrict__ attr,
    const float* __restrict__ q2, const float* __restrict__ kv2,
    const float* __restrict__ xr2,
    const float* __restrict__ bW, float* __restrict__ out, int n_nodes) {
  const int lane = threadIdx.x & 63;
  const int wid = (blockIdx.x * 256 + threadIdx.x) >> 6;
  const int nw = gridDim.x * 4;
  const int slot = lane / 10, h = lane - slot * 10;
  const bool active = slot < 6;
  const unsigned short* evr = (const unsigned short*)attr;

  for (int n = wid; n < n_nodes; n += nw) {
    int p0 = rp[n], deg = rp[n + 1] - p0;
    float qh = q2[(size_t)n * 12 + h];
    int eL = 0, sL = 0;
    if (lane < deg) { eL = seid[p0 + lane]; sL = ssrc[p0 + lane]; }
    float accN = 0.f, accD = 0.f;
    int nit = (deg + 5) / 6;
    for (int t = 0; t < nit; ++t) {
      int i = t * 6 + slot;
      bool val = active && (i < deg);
      int e = 0, s = 0;
      if (i < 64) { e = __shfl(eL, i); s = __shfl(sL, i); }
      else if (val) { e = seid[p0 + i]; s = ssrc[p0 + i]; }
      float evv = 0.f; float2 kv = make_float2(0.f, 0.f);
      if (val) {
        evv = f16_to_f32(evr[(size_t)e * 64 + 50 + h]);
        kv = *(const float2*)(kv2 + (size_t)s * 24 + 2 * h);
      }
      float exv = val ? __expf(qh * (kv.x + evv)) : 0.f;
      accD += exv;
      accN = fmaf(kv.y + evv, exv, accN);
    }
    float D = 0.f, Nn = 0.f;
#pragma unroll
    for (int i2 = 0; i2 < 6; ++i2) {
      D  += __shfl(accD, h + 10 * i2);
      Nn += __shfl(accN, h + 10 * i2);
    }
    float r = (D > 0.f) ? Nn / D : 0.f;
    float o = 0.f;
#pragma unroll
    for (int j = 0; j < 10; ++j) o += __shfl(r, j);
    o *= 0.1f;
    float xr = xr2[n];
    float sbv = bW[0] * o + bW[1] * xr + bW[2] * (o - xr);
    float beta = 1.f / (1.f + __expf(-sbv));
    float y = beta * xr + (1.f - beta) * o;
    if (lane == 0) out[n] = 1.f / (1.f + __expf(-y));
  }
}

// ---------------------------------------------------------------------------
extern "C" void kernel_launch(void* const* d_in, const int* in_sizes, int n_in,
                              void* d_out, int out_size, void* d_ws, size_t ws_size,
                              hipStream_t stream) {
  const float* x    = (const float*)d_in[0];
  float*       attr = (float*)d_in[1];          // overwritten in-place by k_evt
  const int*   ei   = (const int*)d_in[2];
  const int*   batch= (const int*)d_in[3];
  const float* q1W = (const float*)d_in[4];  const float* q1b = (const float*)d_in[5];
  const float* k1W = (const float*)d_in[6];  const float* k1b = (const float*)d_in[7];
  const float* v1W = (const float*)d_in[8];  const float* v1b = (const float*)d_in[9];
  const float* e1W = (const float*)d_in[10];
  const float* s1W = (const float*)d_in[11]; const float* s1b = (const float*)d_in[12];
  const float* b1W = (const float*)d_in[13];
  const float* gnW = (const float*)d_in[14]; const float* gnb = (const float*)d_in[15];
  const float* gnms= (const float*)d_in[16];
  const float* q2W = (const float*)d_in[17]; const float* q2b = (const float*)d_in[18];
  const float* k2W = (const float*)d_in[19]; const float* k2b = (const float*)d_in[20];
  const float* v2W = (const float*)d_in[21]; const float* v2b = (const float*)d_in[22];
  const float* e2W = (const float*)d_in[23];
  const float* s2W = (const float*)d_in[24]; const float* s2b = (const float*)d_in[25];
  const float* b2W = (const float*)d_in[26];

  const int n_nodes = in_sizes[0] / 128;
  const int n_edges = in_sizes[2] / 2;
  float* ws = (float*)d_ws;
  const size_t nn = (size_t)n_nodes;
  const size_t ne = (size_t)n_edges;

  // workspace layout (float units)
  const size_t oQ1  = 0;              // 52*nn
  const size_t oKV1 = 52 * nn;        // 104*nn (k/v interleaved)
  const size_t oXR1 = 156 * nn;       // 8*nn
  const size_t oH1  = 164 * nn;       // 8*nn
  const size_t oQ2  = 172 * nn;       // 12*nn
  const size_t oKV2 = 184 * nn;       // 24*nn
  const size_t oXR2 = 208 * nn;       // nn
  const size_t oSTAT= 209 * nn;       // 1088 (gsum 512 | gsq 512 | gcnt 64)
  const size_t oCNT = oSTAT + 1088;   // nn ints   (contiguous with STAT: 1 memset)
  const size_t oRP  = oCNT + nn;      // nn+1 ints
  const size_t oCUR = oRP + nn + 4;   // nn ints (padded +3 so base stays 16B-aligned)
  const size_t oSEID= oCUR + nn;      // ne ints
  const size_t oSSRC= oSEID + ne;     // ne ints
  const size_t oBSUM= oSSRC + ne;     // ~128 ints (scan block sums)
  // total ~= 212*nn + 2*ne + ~1.3K floats ~= 98 MB

  int* cnt    = (int*)(ws + oCNT);
  int* rp     = (int*)(ws + oRP);
  int* cursor = (int*)(ws + oCUR);
  int* seid   = (int*)(ws + oSEID);
  int* ssrc   = (int*)(ws + oSSRC);
  int* bsum   = (int*)(ws + oBSUM);
  float* gsum = ws + oSTAT;
  float* gsq  = ws + oSTAT + 512;
  float* gcnt = ws + oSTAT + 1024;

  const int nb_nodes = (n_nodes + 255) / 256;
  const int nb_edges = (n_edges + 255) / 256;
  const int nb_scan  = (n_nodes + 1023) / 1024;   // 98 for N=100000 (<=256)
  dim3 gq((n_nodes + 511) / 512, 4);
  const int nb_pers = 2048;  // persistent-wave grid for conv kernels

  // one memset covers stats (1088 f) + cnt (nn ints)
  hipMemsetAsync(ws + oSTAT, 0, (1088 + nn) * sizeof(float), stream);

  k_hist<<<nb_edges, 256, 0, stream>>>(ei, n_edges, cnt);
  k_scansum<<<nb_scan, 256, 0, stream>>>(cnt, bsum, n_nodes);
  k_scantop<<<1, 256, 0, stream>>>(bsum, nb_scan);
  k_scanout<<<nb_scan, 256, 0, stream>>>(cnt, bsum, rp, cursor, n_nodes);
  k_scatter<<<nb_edges, 256, 0, stream>>>(ei, n_edges, cursor, seid, ssrc);

  k_qkvs1<<<gq, 256, 0, stream>>>(x, q1W, q1b, k1W, k1b, v1W, v1b, s1W, s1b,
                                  ws + oQ1, ws + oKV1, ws + oXR1, n_nodes);
  k_evt<<<nb_edges, 256, 0, stream>>>(attr, e1W, e2W, n_edges);

  k_conv1<<<nb_pers, 256, 0, stream>>>(rp, seid, ssrc, attr,
                                       ws + oQ1, ws + oKV1, ws + oXR1,
                                       b1W, ws + oH1, n_nodes);
  k_stats<<<nb_nodes, 256, 0, stream>>>(ws + oH1, batch, gsum, gsq, gcnt, n_nodes);
  k_apply<<<nb_nodes, 256, 0, stream>>>(ws + oH1, batch, gsum, gsq, gcnt,
                                        gnW, gnb, gnms,
                                        q2W, q2b, k2W, k2b, v2W, v2b, s2W, s2b,
                                        ws + oQ2, ws + oKV2, ws + oXR2, n_nodes);
  k_conv2<<<nb_pers, 256, 0, stream>>>(rp, seid, ssrc, attr,
                                       ws + oQ2, ws + oKV2, ws + oXR2,
                                       b2W, (float*)d_out, n_nodes);
}

// Round 5
// 1061.658 us; speedup vs baseline: 1.2262x; 1.0024x over previous
//
#include <hip/hip_runtime.h>
#include <math.h>

// ---------------------------------------------------------------------------
// mTransformerConv: 2x TransformerConv (H=10, c=5 then c=1) + GraphNorm + relu
// N=100000, E=1600000, D_NODE=128, D_EDGE=32, G=64.
// Round 10 (resubmit; R4 was an infra failure): k_conv1 restructured from
// {1 edge/iter, 50 lanes cooperate, 7 shfl/edge} to conv2-style {6 edge-slots
// x 10 heads, dot over 5 channels in-register, 0 shfl/edge, ceil(deg/6)
// iterations}. Cross-lane work moved to a once-per-node epilogue (36+50
// shfls). Index loads prefetched 1 iter ahead.
// ---------------------------------------------------------------------------

#define EPS 1e-5f
#define INV_SQRT5 0.44721359549995794f

__device__ __forceinline__ float f16_to_f32(unsigned short u) {
  union { unsigned short us; _Float16 h; } cv; cv.us = u;
  return (float)cv.h;
}

__device__ __forceinline__ void store40(const float (&acc)[40], int n, int g,
                                        float* __restrict__ q1, float* __restrict__ kv1,
                                        float* __restrict__ xr1) {
#pragma unroll
  for (int c = 0; c < 40; ++c) {
    int ch = g * 40 + c;
    if (ch < 50)        q1[(size_t)n * 52 + ch] = acc[c];
    else if (ch < 100)  kv1[(size_t)n * 104 + 2 * (ch - 50)] = acc[c];
    else if (ch < 150)  kv1[(size_t)n * 104 + 2 * (ch - 100) + 1] = acc[c];
    else if (ch < 155)  xr1[(size_t)n * 8 + (ch - 150)] = acc[c];
  }
}

// ---- K1: q1/kv1/xr1 GEMM. 512 nodes x 40 ch per block ----------------------
__global__ __launch_bounds__(256, 4) void k_qkvs1(
    const float* __restrict__ x,
    const float* __restrict__ qW, const float* __restrict__ qb,
    const float* __restrict__ kW, const float* __restrict__ kb,
    const float* __restrict__ vW, const float* __restrict__ vb,
    const float* __restrict__ sW, const float* __restrict__ sb,
    float* __restrict__ q1, float* __restrict__ kv1,
    float* __restrict__ xr1, int n_nodes) {
  __shared__ __align__(16) float sWt[40 * 128];
  __shared__ float sB[40];
  const int t = threadIdx.x;
  const int g = blockIdx.y;
  const int n0 = blockIdx.x * 512;

  for (int i = t; i < 1280; i += 256) {
    int c = i >> 5, q = i & 31;
    int ch = g * 40 + c;
    float4 w = make_float4(0.f, 0.f, 0.f, 0.f);
    const float* srcr = nullptr;
    if (ch < 50)        srcr = qW + ch * 128;
    else if (ch < 100)  srcr = kW + (ch - 50) * 128;
    else if (ch < 150)  srcr = vW + (ch - 100) * 128;
    else if (ch < 155)  srcr = sW + (ch - 150) * 128;
    if (srcr) w = *(const float4*)(srcr + q * 4);
    *(float4*)&sWt[c * 128 + q * 4] = w;
  }
  if (t < 40) {
    int ch = g * 40 + t;
    float b = 0.f;
    if (ch < 50) b = qb[ch];
    else if (ch < 100) b = kb[ch - 50];
    else if (ch < 150) b = vb[ch - 100];
    else if (ch < 155) b = sb[ch - 150];
    sB[t] = b;
  }
  __syncthreads();

  float accA[40], accB[40];
#pragma unroll
  for (int c = 0; c < 40; ++c) { accA[c] = sB[c]; accB[c] = sB[c]; }
  const int na = n0 + 2 * t, nb = na + 1;
  const bool okA = na < n_nodes, okB = nb < n_nodes;
  const float* xa_p = x + (size_t)(okA ? na : 0) * 128;
  const float* xb_p = x + (size_t)(okB ? nb : 0) * 128;
  const float4* w4 = (const float4*)sWt;

  for (int kc = 0; kc < 128; kc += 8) {
    float4 xa0 = *(const float4*)(xa_p + kc);
    float4 xa1 = *(const float4*)(xa_p + kc + 4);
    float4 xb0 = *(const float4*)(xb_p + kc);
    float4 xb1 = *(const float4*)(xb_p + kc + 4);
    const int base = kc >> 2;
#pragma unroll
    for (int c = 0; c < 40; ++c) {
      float4 w0 = w4[c * 32 + base];
      float4 w1 = w4[c * 32 + base + 1];
      accA[c] = fmaf(w0.x, xa0.x, accA[c]); accA[c] = fmaf(w0.y, xa0.y, accA[c]);
      accA[c] = fmaf(w0.z, xa0.z, accA[c]); accA[c] = fmaf(w0.w, xa0.w, accA[c]);
      accA[c] = fmaf(w1.x, xa1.x, accA[c]); accA[c] = fmaf(w1.y, xa1.y, accA[c]);
      accA[c] = fmaf(w1.z, xa1.z, accA[c]); accA[c] = fmaf(w1.w, xa1.w, accA[c]);
      accB[c] = fmaf(w0.x, xb0.x, accB[c]); accB[c] = fmaf(w0.y, xb0.y, accB[c]);
      accB[c] = fmaf(w0.z, xb0.z, accB[c]); accB[c] = fmaf(w0.w, xb0.w, accB[c]);
      accB[c] = fmaf(w1.x, xb1.x, accB[c]); accB[c] = fmaf(w1.y, xb1.y, accB[c]);
      accB[c] = fmaf(w1.z, xb1.z, accB[c]); accB[c] = fmaf(w1.w, xb1.w, accB[c]);
    }
  }
  if (okA) store40(accA, na, g, q1, kv1, xr1);
  if (okB) store40(accB, nb, g, q1, kv1, xr1);
}

// ---- CSR build -------------------------------------------------------------
__global__ __launch_bounds__(256) void k_hist(const int* __restrict__ ei, int n_edges,
                                              int* __restrict__ cnt) {
  int e = blockIdx.x * 256 + threadIdx.x;
  if (e < n_edges) atomicAdd(&cnt[ei[n_edges + e]], 1);
}

// ---- 3-phase parallel exclusive scan (1024 elems/block) --------------------
__global__ __launch_bounds__(256) void k_scansum(const int* __restrict__ cnt,
                                                 int* __restrict__ bsum, int n) {
  int base = blockIdx.x * 1024 + threadIdx.x * 4;
  int s = 0;
  if (base + 3 < n) {
    int4 v = *(const int4*)(cnt + base);
    s = v.x + v.y + v.z + v.w;
  } else {
    for (int i = base; i < n && i < base + 4; ++i) s += cnt[i];
  }
#pragma unroll
  for (int off = 32; off; off >>= 1) s += __shfl_down(s, off);
  __shared__ int wsum[4];
  if ((threadIdx.x & 63) == 0) wsum[threadIdx.x >> 6] = s;
  __syncthreads();
  if (threadIdx.x == 0) bsum[blockIdx.x] = wsum[0] + wsum[1] + wsum[2] + wsum[3];
}

__global__ __launch_bounds__(256) void k_scantop(int* __restrict__ bsum, int nb) {
  // exclusive scan in place; nb <= 256
  __shared__ int ls[256];
  int tid = threadIdx.x;
  int v = (tid < nb) ? bsum[tid] : 0;
  ls[tid] = v;
  __syncthreads();
  for (int off = 1; off < 256; off <<= 1) {
    int t = (tid >= off) ? ls[tid - off] : 0;
    __syncthreads();
    ls[tid] += t;
    __syncthreads();
  }
  if (tid < nb) bsum[tid] = ls[tid] - v;
}

__global__ __launch_bounds__(256) void k_scanout(const int* __restrict__ cnt,
                                                 const int* __restrict__ bsum,
                                                 int* __restrict__ rp,
                                                 int* __restrict__ cursor, int n) {
  const int tid = threadIdx.x;
  const int lane = tid & 63;
  const int w = tid >> 6;
  int base = blockIdx.x * 1024 + tid * 4;
  int c0 = 0, c1 = 0, c2 = 0, c3 = 0;
  if (base + 3 < n) {
    int4 v = *(const int4*)(cnt + base);
    c0 = v.x; c1 = v.y; c2 = v.z; c3 = v.w;
  } else if (base < n) {
    c0 = cnt[base];
    if (base + 1 < n) c1 = cnt[base + 1];
    if (base + 2 < n) c2 = cnt[base + 2];
    if (base + 3 < n) c3 = cnt[base + 3];
  }
  int s = c0 + c1 + c2 + c3;
  int incl = s;
#pragma unroll
  for (int off = 1; off < 64; off <<= 1) {
    int t = __shfl_up(incl, off);
    if (lane >= off) incl += t;
  }
  __shared__ int wsum[4];
  if (lane == 63) wsum[w] = incl;
  __syncthreads();
  int woff = 0;
#pragma unroll
  for (int j = 0; j < 3; ++j) if (j < w) woff += wsum[j];
  int excl = bsum[blockIdx.x] + woff + (incl - s);
  int4 o;
  o.x = excl; o.y = o.x + c0; o.z = o.y + c1; o.w = o.z + c2;
  if (base + 3 < n) {
    *(int4*)(rp + base) = o;
    *(int4*)(cursor + base) = o;
  } else if (base < n) {
    rp[base] = o.x; cursor[base] = o.x;
    if (base + 1 < n) { rp[base + 1] = o.y; cursor[base + 1] = o.y; }
    if (base + 2 < n) { rp[base + 2] = o.z; cursor[base + 2] = o.z; }
  }
  if (base < n && base + 4 >= n) rp[n] = excl + s;  // total (last thread only)
}

__global__ __launch_bounds__(256) void k_scatter(const int* __restrict__ ei, int n_edges,
                                                 int* __restrict__ cursor,
                                                 int* __restrict__ seid,
                                                 int* __restrict__ ssrc) {
  int e = blockIdx.x * 256 + threadIdx.x;
  if (e >= n_edges) return;
  int s = ei[e];
  int d = ei[n_edges + e];
  int p = atomicAdd(&cursor[d], 1);
  seid[p] = e;
  ssrc[p] = s;
}

// ---- K-evt: ev1(50)+ev2(10) = attr @ W^T, stored f16 in place over attr ----
__global__ __launch_bounds__(256) void k_evt(
    float* attr, const float* __restrict__ e1W, const float* __restrict__ e2W,
    int n_edges) {
  int e = blockIdx.x * 256 + threadIdx.x;
  if (e >= n_edges) return;
  const float4* ar = (const float4*)(attr + (size_t)e * 32);
  float4 a[8];
#pragma unroll
  for (int j = 0; j < 8; ++j) a[j] = ar[j];
  unsigned int d[30];
#pragma unroll
  for (int c2 = 0; c2 < 30; ++c2) {
    int c0 = 2 * c2, c1 = 2 * c2 + 1;
    const float* w0 = (c0 < 50) ? (e1W + c0 * 32) : (e2W + (c0 - 50) * 32);
    const float* w1 = (c1 < 50) ? (e1W + c1 * 32) : (e2W + (c1 - 50) * 32);
    float acc0 = 0.f, acc1 = 0.f;
#pragma unroll
    for (int j = 0; j < 8; ++j) {
      float4 wa = *(const float4*)(w0 + 4 * j);
      float4 wb = *(const float4*)(w1 + 4 * j);
      acc0 = fmaf(wa.x, a[j].x, acc0); acc0 = fmaf(wa.y, a[j].y, acc0);
      acc0 = fmaf(wa.z, a[j].z, acc0); acc0 = fmaf(wa.w, a[j].w, acc0);
      acc1 = fmaf(wb.x, a[j].x, acc1); acc1 = fmaf(wb.y, a[j].y, acc1);
      acc1 = fmaf(wb.z, a[j].z, acc1); acc1 = fmaf(wb.w, a[j].w, acc1);
    }
    union { _Float16 h[2]; unsigned int u; } p;
    p.h[0] = (_Float16)acc0; p.h[1] = (_Float16)acc1;
    d[c2] = p.u;
  }
  unsigned int* row = (unsigned int*)(attr + (size_t)e * 32);
#pragma unroll
  for (int k = 0; k < 7; ++k)
    *(uint4*)(row + 4 * k) = make_uint4(d[4 * k], d[4 * k + 1], d[4 * k + 2], d[4 * k + 3]);
  *(uint2*)(row + 28) = make_uint2(d[28], d[29]);
}

// ---- K-conv1: 6 edge-slots x 10 heads, 5-ch dot in-register ----------------
__global__ __launch_bounds__(256) void k_conv1(
    const int* __restrict__ rp, const int* __restrict__ seid,
    const int* __restrict__ ssrc, const float* __restrict__ attr,
    const float* __restrict__ q1, const float* __restrict__ kv1,
    const float* __restrict__ xr1,
    const float* __restrict__ bW, float* __restrict__ h1, int n_nodes) {
  const int lane = threadIdx.x & 63;
  const int wid = (blockIdx.x * 256 + threadIdx.x) >> 6;
  const int nw = gridDim.x * 4;
  const int slot = lane / 10;
  const int h = lane - slot * 10;      // head 0..9
  const bool active = slot < 6;
  const int cs = 5 * h;                // start channel of this head
  const unsigned int* evu = (const unsigned int*)attr;

  // beta weights (broadcast, cached)
  float bw0[5], bw1[5], bw2[5];
#pragma unroll
  for (int c = 0; c < 5; ++c) { bw0[c] = bW[c]; bw1[c] = bW[5 + c]; bw2[c] = bW[10 + c]; }

  for (int n = wid; n < n_nodes; n += nw) {
    const int p0 = rp[n], deg = rp[n + 1] - p0;
    const float* qp = q1 + (size_t)n * 52 + cs;
    const float q0 = qp[0], q1v = qp[1], q2v = qp[2], q3v = qp[3], q4v = qp[4];

    float accD = 0.f, aN0 = 0.f, aN1 = 0.f, aN2 = 0.f, aN3 = 0.f, aN4 = 0.f;
    const int nit = (deg + 5) / 6;
    int i = slot;
    bool val = active && (i < deg);
    int e = 0, s = 0;
    if (val) { e = seid[p0 + i]; s = ssrc[p0 + i]; }
    for (int t = 0; t < nit; ++t) {
      // prefetch next iteration's indices
      int in = i + 6;
      bool valn = active && (in < deg);
      int en = 0, sn = 0;
      if (valn) { en = seid[p0 + in]; sn = ssrc[p0 + in]; }
      // gather ev (5 f16 packed in 3 uints) and kv (5 float2)
      float ev0 = 0.f, ev1 = 0.f, ev2 = 0.f, ev3 = 0.f, ev4 = 0.f;
      float2 kv0 = make_float2(0.f, 0.f), kv1v = kv0, kv2v = kv0, kv3v = kv0, kv4v = kv0;
      if (val) {
        const unsigned int* er = evu + (size_t)e * 32 + (cs >> 1);
        unsigned int u0 = er[0], u1 = er[1], u2 = er[2];
        if (cs & 1) {
          ev0 = f16_to_f32((unsigned short)(u0 >> 16));
          ev1 = f16_to_f32((unsigned short)(u1 & 0xffff));
          ev2 = f16_to_f32((unsigned short)(u1 >> 16));
          ev3 = f16_to_f32((unsigned short)(u2 & 0xffff));
          ev4 = f16_to_f32((unsigned short)(u2 >> 16));
        } else {
          ev0 = f16_to_f32((unsigned short)(u0 & 0xffff));
          ev1 = f16_to_f32((unsigned short)(u0 >> 16));
          ev2 = f16_to_f32((unsigned short)(u1 & 0xffff));
          ev3 = f16_to_f32((unsigned short)(u1 >> 16));
          ev4 = f16_to_f32((unsigned short)(u2 & 0xffff));
        }
        const float* kvp = kv1 + (size_t)s * 104 + 10 * h;
        kv0 = *(const float2*)(kvp);
        kv1v = *(const float2*)(kvp + 2);
        kv2v = *(const float2*)(kvp + 4);
        kv3v = *(const float2*)(kvp + 6);
        kv4v = *(const float2*)(kvp + 8);
      }
      float al = q0 * (kv0.x + ev0);
      al = fmaf(q1v, kv1v.x + ev1, al);
      al = fmaf(q2v, kv2v.x + ev2, al);
      al = fmaf(q3v, kv3v.x + ev3, al);
      al = fmaf(q4v, kv4v.x + ev4, al);
      float ex = val ? __expf(al * INV_SQRT5) : 0.f;
      accD += ex;
      aN0 = fmaf(kv0.y + ev0, ex, aN0);
      aN1 = fmaf(kv1v.y + ev1, ex, aN1);
      aN2 = fmaf(kv2v.y + ev2, ex, aN2);
      aN3 = fmaf(kv3v.y + ev3, ex, aN3);
      aN4 = fmaf(kv4v.y + ev4, ex, aN4);
      i = in; val = valn; e = en; s = sn;
    }
    // slot-reduce (6 slots) for this lane's head
    float D = 0.f, N0 = 0.f, N1 = 0.f, N2 = 0.f, N3 = 0.f, N4 = 0.f;
#pragma unroll
    for (int i2 = 0; i2 < 6; ++i2) {
      int sl = h + 10 * i2;
      D  += __shfl(accD, sl);
      N0 += __shfl(aN0, sl); N1 += __shfl(aN1, sl); N2 += __shfl(aN2, sl);
      N3 += __shfl(aN3, sl); N4 += __shfl(aN4, sl);
    }
    float rD = (D > 0.f) ? (1.f / D) : 0.f;
    float r0 = N0 * rD, r1 = N1 * rD, r2 = N2 * rD, r3 = N3 * rD, r4 = N4 * rD;
    // head-mean (10 heads live on lanes 0..9)
    float o0 = 0.f, o1 = 0.f, o2 = 0.f, o3 = 0.f, o4 = 0.f;
#pragma unroll
    for (int hh = 0; hh < 10; ++hh) {
      o0 += __shfl(r0, hh); o1 += __shfl(r1, hh); o2 += __shfl(r2, hh);
      o3 += __shfl(r3, hh); o4 += __shfl(r4, hh);
    }
    o0 *= 0.1f; o1 *= 0.1f; o2 *= 0.1f; o3 *= 0.1f; o4 *= 0.1f;
    float4 xv = *(const float4*)(xr1 + (size_t)n * 8);
    float x4 = xr1[(size_t)n * 8 + 4];
    float sb = bw0[0] * o0 + bw1[0] * xv.x + bw2[0] * (o0 - xv.x);
    sb += bw0[1] * o1 + bw1[1] * xv.y + bw2[1] * (o1 - xv.y);
    sb += bw0[2] * o2 + bw1[2] * xv.z + bw2[2] * (o2 - xv.z);
    sb += bw0[3] * o3 + bw1[3] * xv.w + bw2[3] * (o3 - xv.w);
    sb += bw0[4] * o4 + bw1[4] * x4 + bw2[4] * (o4 - x4);
    float beta = 1.f / (1.f + __expf(-sb));
    if (lane < 5) {
      float ow = (lane == 0) ? o0 : (lane == 1) ? o1 : (lane == 2) ? o2
               : (lane == 3) ? o3 : o4;
      float xw = (lane == 0) ? xv.x : (lane == 1) ? xv.y : (lane == 2) ? xv.z
               : (lane == 3) ? xv.w : x4;
      h1[(size_t)n * 8 + lane] = beta * xw + (1.f - beta) * ow;
    }
  }
}

// ---- GraphNorm stats, single pass (sum, sumsq, count) ----------------------
__global__ __launch_bounds__(256) void k_stats(
    const float* __restrict__ h1, const int* __restrict__ batch,
    float* __restrict__ gsum, float* __restrict__ gsq,
    float* __restrict__ gcnt, int n_nodes) {
  int n = blockIdx.x * 256 + threadIdx.x;
  bool act = n < n_nodes;
  int g = act ? batch[n] : 0;
  float v[5], s2[5], one = act ? 1.f : 0.f;
#pragma unroll
  for (int c = 0; c < 5; ++c) {
    v[c] = act ? h1[(size_t)n * 8 + c] : 0.f;
    s2[c] = v[c] * v[c];
  }
  int g0 = __shfl(g, 0);
  bool uni = __all((!act) || (g == g0));
  if (uni) {
#pragma unroll
    for (int off = 32; off; off >>= 1) {
#pragma unroll
      for (int c = 0; c < 5; ++c) {
        v[c] += __shfl_down(v[c], off);
        s2[c] += __shfl_down(s2[c], off);
      }
      one += __shfl_down(one, off);
    }
    if ((threadIdx.x & 63) == 0) {
#pragma unroll
      for (int c = 0; c < 5; ++c) {
        atomicAdd(&gsum[g0 * 8 + c], v[c]);
        atomicAdd(&gsq[g0 * 8 + c], s2[c]);
      }
      atomicAdd(&gcnt[g0], one);
    }
  } else if (act) {
#pragma unroll
    for (int c = 0; c < 5; ++c) {
      atomicAdd(&gsum[g * 8 + c], v[c]);
      atomicAdd(&gsq[g * 8 + c], s2[c]);
    }
    atomicAdd(&gcnt[g], 1.f);
  }
}

// ---- apply norm + relu + q2/kv2/xr2 ----------------------------------------
__global__ __launch_bounds__(256) void k_apply(
    const float* __restrict__ h1, const int* __restrict__ batch,
    const float* __restrict__ gsum, const float* __restrict__ gsq,
    const float* __restrict__ gcnt,
    const float* __restrict__ gnw, const float* __restrict__ gnb,
    const float* __restrict__ gnms,
    const float* __restrict__ q2W, const float* __restrict__ q2b,
    const float* __restrict__ k2W, const float* __restrict__ k2b,
    const float* __restrict__ v2W, const float* __restrict__ v2b,
    const float* __restrict__ s2W, const float* __restrict__ s2b,
    float* __restrict__ q2, float* __restrict__ kv2,
    float* __restrict__ xr2, int n_nodes) {
  int n = blockIdx.x * 256 + threadIdx.x;
  if (n >= n_nodes) return;
  int g = batch[n];
  float rc = 1.f / fmaxf(gcnt[g], 1.f);
  float r[5];
#pragma unroll
  for (int c = 0; c < 5; ++c) {
    float ms = gnms[c];
    float mean = gsum[g * 8 + c] * rc;
    float var = gsq[g * 8 + c] * rc - mean * mean * ms * (2.f - ms);
    var = fmaxf(var, 0.f);
    float o = h1[(size_t)n * 8 + c] - mean * ms;
    float y = gnw[c] * o * rsqrtf(var + EPS) + gnb[c];
    r[c] = fmaxf(y, 0.f);
  }
#pragma unroll
  for (int h = 0; h < 10; ++h) {
    float aq = q2b[h], ak = k2b[h], av = v2b[h];
#pragma unroll
    for (int i = 0; i < 5; ++i) {
      aq = fmaf(r[i], q2W[h * 5 + i], aq);
      ak = fmaf(r[i], k2W[h * 5 + i], ak);
      av = fmaf(r[i], v2W[h * 5 + i], av);
    }
    q2[(size_t)n * 12 + h] = aq;
    kv2[(size_t)n * 24 + 2 * h]     = ak;
    kv2[(size_t)n * 24 + 2 * h + 1] = av;
  }
  float s = s2b[0];
#pragma unroll
  for (int i = 0; i < 5; ++i) s = fmaf(r[i], s2W[i], s);
  xr2[n] = s;
}

// ---- K-conv2: persistent wave per node, 6 edges x 10 heads -----------------
__global__ __launch_bounds__(256) void k_conv2(
    const int* __restrict__ rp, const int* __restrict__ seid,
    const int* __restrict__ ssrc, const float* __restrict__ attr,
    const float* __restrict__ q2, const float* __restrict__ kv2,
    const float* __restrict__ xr2,
    const float* __restrict__ bW, float* __restrict__ out, int n_nodes) {
  const int lane = threadIdx.x & 63;
  const int wid = (blockIdx.x * 256 + threadIdx.x) >> 6;
  const int nw = gridDim.x * 4;
  const int slot = lane / 10, h = lane - slot * 10;
  const bool active = slot < 6;
  const unsigned short* evr = (const unsigned short*)attr;

  for (int n = wid; n < n_nodes; n += nw) {
    int p0 = rp[n], deg = rp[n + 1] - p0;
    float qh = q2[(size_t)n * 12 + h];
    int eL = 0, sL = 0;
    if (lane < deg) { eL = seid[p0 + lane]; sL = ssrc[p0 + lane]; }
    float accN = 0.f, accD = 0.f;
    int nit = (deg + 5) / 6;
    for (int t = 0; t < nit; ++t) {
      int i = t * 6 + slot;
      bool val = active && (i < deg);
      int e = 0, s = 0;
      if (i < 64) { e = __shfl(eL, i); s = __shfl(sL, i); }
      else if (val) { e = seid[p0 + i]; s = ssrc[p0 + i]; }
      float evv = 0.f; float2 kv = make_float2(0.f, 0.f);
      if (val) {
        evv = f16_to_f32(evr[(size_t)e * 64 + 50 + h]);
        kv = *(const float2*)(kv2 + (size_t)s * 24 + 2 * h);
      }
      float exv = val ? __expf(qh * (kv.x + evv)) : 0.f;
      accD += exv;
      accN = fmaf(kv.y + evv, exv, accN);
    }
    float D = 0.f, Nn = 0.f;
#pragma unroll
    for (int i2 = 0; i2 < 6; ++i2) {
      D  += __shfl(accD, h + 10 * i2);
      Nn += __shfl(accN, h + 10 * i2);
    }
    float r = (D > 0.f) ? Nn / D : 0.f;
    float o = 0.f;
#pragma unroll
    for (int j = 0; j < 10; ++j) o += __shfl(r, j);
    o *= 0.1f;
    float xr = xr2[n];
    float sbv = bW[0] * o + bW[1] * xr + bW[2] * (o - xr);
    float beta = 1.f / (1.f + __expf(-sbv));
    float y = beta * xr + (1.f - beta) * o;
    if (lane == 0) out[n] = 1.f / (1.f + __expf(-y));
  }
}

// ---------------------------------------------------------------------------
extern "C" void kernel_launch(void* const* d_in, const int* in_sizes, int n_in,
                              void* d_out, int out_size, void* d_ws, size_t ws_size,
                              hipStream_t stream) {
  const float* x    = (const float*)d_in[0];
  float*       attr = (float*)d_in[1];          // overwritten in-place by k_evt
  const int*   ei   = (const int*)d_in[2];
  const int*   batch= (const int*)d_in[3];
  const float* q1W = (const float*)d_in[4];  const float* q1b = (const float*)d_in[5];
  const float* k1W = (const float*)d_in[6];  const float* k1b = (const float*)d_in[7];
  const float* v1W = (const float*)d_in[8];  const float* v1b = (const float*)d_in[9];
  const float* e1W = (const float*)d_in[10];
  const float* s1W = (const float*)d_in[11]; const float* s1b = (const float*)d_in[12];
  const float* b1W = (const float*)d_in[13];
  const float* gnW = (const float*)d_in[14]; const float* gnb = (const float*)d_in[15];
  const float* gnms= (const float*)d_in[16];
  const float* q2W = (const float*)d_in[17]; const float* q2b = (const float*)d_in[18];
  const float* k2W = (const float*)d_in[19]; const float* k2b = (const float*)d_in[20];
  const float* v2W = (const float*)d_in[21]; const float* v2b = (const float*)d_in[22];
  const float* e2W = (const float*)d_in[23];
  const float* s2W = (const float*)d_in[24]; const float* s2b = (const float*)d_in[25];
  const float* b2W = (const float*)d_in[26];

  const int n_nodes = in_sizes[0] / 128;
  const int n_edges = in_sizes[2] / 2;
  float* ws = (float*)d_ws;
  const size_t nn = (size_t)n_nodes;
  const size_t ne = (size_t)n_edges;

  // workspace layout (float units)
  const size_t oQ1  = 0;              // 52*nn
  const size_t oKV1 = 52 * nn;        // 104*nn (k/v interleaved)
  const size_t oXR1 = 156 * nn;       // 8*nn
  const size_t oH1  = 164 * nn;       // 8*nn
  const size_t oQ2  = 172 * nn;       // 12*nn
  const size_t oKV2 = 184 * nn;       // 24*nn
  const size_t oXR2 = 208 * nn;       // nn
  const size_t oSTAT= 209 * nn;       // 1088 (gsum 512 | gsq 512 | gcnt 64)
  const size_t oCNT = oSTAT + 1088;   // nn ints   (contiguous with STAT: 1 memset)
  const size_t oRP  = oCNT + nn;      // nn+1 ints
  const size_t oCUR = oRP + nn + 4;   // nn ints (padded so base stays 16B-aligned)
  const size_t oSEID= oCUR + nn;      // ne ints
  const size_t oSSRC= oSEID + ne;     // ne ints
  const size_t oBSUM= oSSRC + ne;     // ~128 ints (scan block sums)

  int* cnt    = (int*)(ws + oCNT);
  int* rp     = (int*)(ws + oRP);
  int* cursor = (int*)(ws + oCUR);
  int* seid   = (int*)(ws + oSEID);
  int* ssrc   = (int*)(ws + oSSRC);
  int* bsum   = (int*)(ws + oBSUM);
  float* gsum = ws + oSTAT;
  float* gsq  = ws + oSTAT + 512;
  float* gcnt = ws + oSTAT + 1024;

  const int nb_nodes = (n_nodes + 255) / 256;
  const int nb_edges = (n_edges + 255) / 256;
  const int nb_scan  = (n_nodes + 1023) / 1024;   // 98 for N=100000 (<=256)
  dim3 gq((n_nodes + 511) / 512, 4);
  const int nb_pers = 2048;  // persistent-wave grid for conv kernels

  // one memset covers stats (1088 f) + cnt (nn ints)
  hipMemsetAsync(ws + oSTAT, 0, (1088 + nn) * sizeof(float), stream);

  k_hist<<<nb_edges, 256, 0, stream>>>(ei, n_edges, cnt);
  k_scansum<<<nb_scan, 256, 0, stream>>>(cnt, bsum, n_nodes);
  k_scantop<<<1, 256, 0, stream>>>(bsum, nb_scan);
  k_scanout<<<nb_scan, 256, 0, stream>>>(cnt, bsum, rp, cursor, n_nodes);
  k_scatter<<<nb_edges, 256, 0, stream>>>(ei, n_edges, cursor, seid, ssrc);

  k_qkvs1<<<gq, 256, 0, stream>>>(x, q1W, q1b, k1W, k1b, v1W, v1b, s1W, s1b,
                                  ws + oQ1, ws + oKV1, ws + oXR1, n_nodes);
  k_evt<<<nb_edges, 256, 0, stream>>>(attr, e1W, e2W, n_edges);

  k_conv1<<<nb_pers, 256, 0, stream>>>(rp, seid, ssrc, attr,
                                       ws + oQ1, ws + oKV1, ws + oXR1,
                                       b1W, ws + oH1, n_nodes);
  k_stats<<<nb_nodes, 256, 0, stream>>>(ws + oH1, batch, gsum, gsq, gcnt, n_nodes);
  k_apply<<<nb_nodes, 256, 0, stream>>>(ws + oH1, batch, gsum, gsq, gcnt,
                                        gnW, gnb, gnms,
                                        q2W, q2b, k2W, k2b, v2W, v2b, s2W, s2b,
                                        ws + oQ2, ws + oKV2, ws + oXR2, n_nodes);
  k_conv2<<<nb_pers, 256, 0, stream>>>(rp, seid, ssrc, attr,
                                       ws + oQ2, ws + oKV2, ws + oXR2,
                                       b2W, (float*)d_out, n_nodes);
}

// Round 7
// 1043.591 us; speedup vs baseline: 1.2474x; 1.0173x over previous
//
#include <hip/hip_runtime.h>
#include <math.h>

// ---------------------------------------------------------------------------
// mTransformerConv: 2x TransformerConv (H=10, c=5 then c=1) + GraphNorm + relu
// N=100000, E=1600000, D_NODE=128, D_EDGE=32, G=64.
// Round 11 (resubmit; R6 was an infra failure): cut gathered BYTES (conv
// kernels are gather-traffic-bound, not instruction-bound — R10 lesson):
// kv1/kv2 stored f16 (halves conv1/conv2 per-edge gather + qkvs1 writes).
// qkvs1 grid transposed to dim3(4,chunks) so the 4 weight-group siblings of
// an x-chunk are adjacent block IDs -> x fetched ~once from HBM instead of 4x
// (FETCH was 236MB for a 51MB matrix).
// ---------------------------------------------------------------------------

#define EPS 1e-5f
#define INV_SQRT5 0.44721359549995794f

__device__ __forceinline__ float f16_to_f32(unsigned short u) {
  union { unsigned short us; _Float16 h; } cv; cv.us = u;
  return (float)cv.h;
}
__device__ __forceinline__ unsigned short f32_to_f16(float f) {
  union { unsigned short us; _Float16 h; } cv; cv.h = (_Float16)f;
  return cv.us;
}

__device__ __forceinline__ void store40(const float (&acc)[40], int n, int g,
                                        float* __restrict__ q1,
                                        unsigned short* __restrict__ kv1h,
                                        float* __restrict__ xr1) {
#pragma unroll
  for (int c = 0; c < 40; ++c) {
    int ch = g * 40 + c;
    if (ch < 50)        q1[(size_t)n * 52 + ch] = acc[c];
    else if (ch < 100)  kv1h[(size_t)n * 104 + 2 * (ch - 50)] = f32_to_f16(acc[c]);
    else if (ch < 150)  kv1h[(size_t)n * 104 + 2 * (ch - 100) + 1] = f32_to_f16(acc[c]);
    else if (ch < 155)  xr1[(size_t)n * 8 + (ch - 150)] = acc[c];
  }
}

// ---- K1: q1/kv1/xr1 GEMM. 512 nodes x 40 ch per block ----------------------
// grid = (4 weight-groups, node-chunks): siblings adjacent -> x L3-shared.
__global__ __launch_bounds__(256, 4) void k_qkvs1(
    const float* __restrict__ x,
    const float* __restrict__ qW, const float* __restrict__ qb,
    const float* __restrict__ kW, const float* __restrict__ kb,
    const float* __restrict__ vW, const float* __restrict__ vb,
    const float* __restrict__ sW, const float* __restrict__ sb,
    float* __restrict__ q1, unsigned short* __restrict__ kv1h,
    float* __restrict__ xr1, int n_nodes) {
  __shared__ __align__(16) float sWt[40 * 128];
  __shared__ float sB[40];
  const int t = threadIdx.x;
  const int g = blockIdx.x;
  const int n0 = blockIdx.y * 512;

  for (int i = t; i < 1280; i += 256) {
    int c = i >> 5, q = i & 31;
    int ch = g * 40 + c;
    float4 w = make_float4(0.f, 0.f, 0.f, 0.f);
    const float* srcr = nullptr;
    if (ch < 50)        srcr = qW + ch * 128;
    else if (ch < 100)  srcr = kW + (ch - 50) * 128;
    else if (ch < 150)  srcr = vW + (ch - 100) * 128;
    else if (ch < 155)  srcr = sW + (ch - 150) * 128;
    if (srcr) w = *(const float4*)(srcr + q * 4);
    *(float4*)&sWt[c * 128 + q * 4] = w;
  }
  if (t < 40) {
    int ch = g * 40 + t;
    float b = 0.f;
    if (ch < 50) b = qb[ch];
    else if (ch < 100) b = kb[ch - 50];
    else if (ch < 150) b = vb[ch - 100];
    else if (ch < 155) b = sb[ch - 150];
    sB[t] = b;
  }
  __syncthreads();

  float accA[40], accB[40];
#pragma unroll
  for (int c = 0; c < 40; ++c) { accA[c] = sB[c]; accB[c] = sB[c]; }
  const int na = n0 + 2 * t, nb = na + 1;
  const bool okA = na < n_nodes, okB = nb < n_nodes;
  const float* xa_p = x + (size_t)(okA ? na : 0) * 128;
  const float* xb_p = x + (size_t)(okB ? nb : 0) * 128;
  const float4* w4 = (const float4*)sWt;

  for (int kc = 0; kc < 128; kc += 8) {
    float4 xa0 = *(const float4*)(xa_p + kc);
    float4 xa1 = *(const float4*)(xa_p + kc + 4);
    float4 xb0 = *(const float4*)(xb_p + kc);
    float4 xb1 = *(const float4*)(xb_p + kc + 4);
    const int base = kc >> 2;
#pragma unroll
    for (int c = 0; c < 40; ++c) {
      float4 w0 = w4[c * 32 + base];
      float4 w1 = w4[c * 32 + base + 1];
      accA[c] = fmaf(w0.x, xa0.x, accA[c]); accA[c] = fmaf(w0.y, xa0.y, accA[c]);
      accA[c] = fmaf(w0.z, xa0.z, accA[c]); accA[c] = fmaf(w0.w, xa0.w, accA[c]);
      accA[c] = fmaf(w1.x, xa1.x, accA[c]); accA[c] = fmaf(w1.y, xa1.y, accA[c]);
      accA[c] = fmaf(w1.z, xa1.z, accA[c]); accA[c] = fmaf(w1.w, xa1.w, accA[c]);
      accB[c] = fmaf(w0.x, xb0.x, accB[c]); accB[c] = fmaf(w0.y, xb0.y, accB[c]);
      accB[c] = fmaf(w0.z, xb0.z, accB[c]); accB[c] = fmaf(w0.w, xb0.w, accB[c]);
      accB[c] = fmaf(w1.x, xb1.x, accB[c]); accB[c] = fmaf(w1.y, xb1.y, accB[c]);
      accB[c] = fmaf(w1.z, xb1.z, accB[c]); accB[c] = fmaf(w1.w, xb1.w, accB[c]);
    }
  }
  if (okA) store40(accA, na, g, q1, kv1h, xr1);
  if (okB) store40(accB, nb, g, q1, kv1h, xr1);
}

// ---- CSR build -------------------------------------------------------------
__global__ __launch_bounds__(256) void k_hist(const int* __restrict__ ei, int n_edges,
                                              int* __restrict__ cnt) {
  int e = blockIdx.x * 256 + threadIdx.x;
  if (e < n_edges) atomicAdd(&cnt[ei[n_edges + e]], 1);
}

// ---- 3-phase parallel exclusive scan (1024 elems/block) --------------------
__global__ __launch_bounds__(256) void k_scansum(const int* __restrict__ cnt,
                                                 int* __restrict__ bsum, int n) {
  int base = blockIdx.x * 1024 + threadIdx.x * 4;
  int s = 0;
  if (base + 3 < n) {
    int4 v = *(const int4*)(cnt + base);
    s = v.x + v.y + v.z + v.w;
  } else {
    for (int i = base; i < n && i < base + 4; ++i) s += cnt[i];
  }
#pragma unroll
  for (int off = 32; off; off >>= 1) s += __shfl_down(s, off);
  __shared__ int wsum[4];
  if ((threadIdx.x & 63) == 0) wsum[threadIdx.x >> 6] = s;
  __syncthreads();
  if (threadIdx.x == 0) bsum[blockIdx.x] = wsum[0] + wsum[1] + wsum[2] + wsum[3];
}

__global__ __launch_bounds__(256) void k_scantop(int* __restrict__ bsum, int nb) {
  __shared__ int ls[256];
  int tid = threadIdx.x;
  int v = (tid < nb) ? bsum[tid] : 0;
  ls[tid] = v;
  __syncthreads();
  for (int off = 1; off < 256; off <<= 1) {
    int t = (tid >= off) ? ls[tid - off] : 0;
    __syncthreads();
    ls[tid] += t;
    __syncthreads();
  }
  if (tid < nb) bsum[tid] = ls[tid] - v;
}

__global__ __launch_bounds__(256) void k_scanout(const int* __restrict__ cnt,
                                                 const int* __restrict__ bsum,
                                                 int* __restrict__ rp,
                                                 int* __restrict__ cursor, int n) {
  const int tid = threadIdx.x;
  const int lane = tid & 63;
  const int w = tid >> 6;
  int base = blockIdx.x * 1024 + tid * 4;
  int c0 = 0, c1 = 0, c2 = 0, c3 = 0;
  if (base + 3 < n) {
    int4 v = *(const int4*)(cnt + base);
    c0 = v.x; c1 = v.y; c2 = v.z; c3 = v.w;
  } else if (base < n) {
    c0 = cnt[base];
    if (base + 1 < n) c1 = cnt[base + 1];
    if (base + 2 < n) c2 = cnt[base + 2];
    if (base + 3 < n) c3 = cnt[base + 3];
  }
  int s = c0 + c1 + c2 + c3;
  int incl = s;
#pragma unroll
  for (int off = 1; off < 64; off <<= 1) {
    int t = __shfl_up(incl, off);
    if (lane >= off) incl += t;
  }
  __shared__ int wsum[4];
  if (lane == 63) wsum[w] = incl;
  __syncthreads();
  int woff = 0;
#pragma unroll
  for (int j = 0; j < 3; ++j) if (j < w) woff += wsum[j];
  int excl = bsum[blockIdx.x] + woff + (incl - s);
  int4 o;
  o.x = excl; o.y = o.x + c0; o.z = o.y + c1; o.w = o.z + c2;
  if (base + 3 < n) {
    *(int4*)(rp + base) = o;
    *(int4*)(cursor + base) = o;
  } else if (base < n) {
    rp[base] = o.x; cursor[base] = o.x;
    if (base + 1 < n) { rp[base + 1] = o.y; cursor[base + 1] = o.y; }
    if (base + 2 < n) { rp[base + 2] = o.z; cursor[base + 2] = o.z; }
  }
  if (base < n && base + 4 >= n) rp[n] = excl + s;  // total (last thread only)
}

__global__ __launch_bounds__(256) void k_scatter(const int* __restrict__ ei, int n_edges,
                                                 int* __restrict__ cursor,
                                                 int* __restrict__ seid,
                                                 int* __restrict__ ssrc) {
  int e = blockIdx.x * 256 + threadIdx.x;
  if (e >= n_edges) return;
  int s = ei[e];
  int d = ei[n_edges + e];
  int p = atomicAdd(&cursor[d], 1);
  seid[p] = e;
  ssrc[p] = s;
}

// ---- K-evt: ev1(50)+ev2(10) = attr @ W^T, stored f16 in place over attr ----
__global__ __launch_bounds__(256) void k_evt(
    float* attr, const float* __restrict__ e1W, const float* __restrict__ e2W,
    int n_edges) {
  int e = blockIdx.x * 256 + threadIdx.x;
  if (e >= n_edges) return;
  const float4* ar = (const float4*)(attr + (size_t)e * 32);
  float4 a[8];
#pragma unroll
  for (int j = 0; j < 8; ++j) a[j] = ar[j];
  unsigned int d[30];
#pragma unroll
  for (int c2 = 0; c2 < 30; ++c2) {
    int c0 = 2 * c2, c1 = 2 * c2 + 1;
    const float* w0 = (c0 < 50) ? (e1W + c0 * 32) : (e2W + (c0 - 50) * 32);
    const float* w1 = (c1 < 50) ? (e1W + c1 * 32) : (e2W + (c1 - 50) * 32);
    float acc0 = 0.f, acc1 = 0.f;
#pragma unroll
    for (int j = 0; j < 8; ++j) {
      float4 wa = *(const float4*)(w0 + 4 * j);
      float4 wb = *(const float4*)(w1 + 4 * j);
      acc0 = fmaf(wa.x, a[j].x, acc0); acc0 = fmaf(wa.y, a[j].y, acc0);
      acc0 = fmaf(wa.z, a[j].z, acc0); acc0 = fmaf(wa.w, a[j].w, acc0);
      acc1 = fmaf(wb.x, a[j].x, acc1); acc1 = fmaf(wb.y, a[j].y, acc1);
      acc1 = fmaf(wb.z, a[j].z, acc1); acc1 = fmaf(wb.w, a[j].w, acc1);
    }
    union { _Float16 h[2]; unsigned int u; } p;
    p.h[0] = (_Float16)acc0; p.h[1] = (_Float16)acc1;
    d[c2] = p.u;
  }
  unsigned int* row = (unsigned int*)(attr + (size_t)e * 32);
#pragma unroll
  for (int k = 0; k < 7; ++k)
    *(uint4*)(row + 4 * k) = make_uint4(d[4 * k], d[4 * k + 1], d[4 * k + 2], d[4 * k + 3]);
  *(uint2*)(row + 28) = make_uint2(d[28], d[29]);
}

// ---- K-conv1: 6 edge-slots x 10 heads, 5-ch dot in-register, f16 kv --------
__global__ __launch_bounds__(256) void k_conv1(
    const int* __restrict__ rp, const int* __restrict__ seid,
    const int* __restrict__ ssrc, const float* __restrict__ attr,
    const float* __restrict__ q1, const unsigned short* __restrict__ kv1h,
    const float* __restrict__ xr1,
    const float* __restrict__ bW, float* __restrict__ h1, int n_nodes) {
  const int lane = threadIdx.x & 63;
  const int wid = (blockIdx.x * 256 + threadIdx.x) >> 6;
  const int nw = gridDim.x * 4;
  const int slot = lane / 10;
  const int h = lane - slot * 10;      // head 0..9
  const bool active = slot < 6;
  const int cs = 5 * h;                // start channel of this head
  const unsigned int* evu = (const unsigned int*)attr;

  float bw0[5], bw1[5], bw2[5];
#pragma unroll
  for (int c = 0; c < 5; ++c) { bw0[c] = bW[c]; bw1[c] = bW[5 + c]; bw2[c] = bW[10 + c]; }

  for (int n = wid; n < n_nodes; n += nw) {
    const int p0 = rp[n], deg = rp[n + 1] - p0;
    const float* qp = q1 + (size_t)n * 52 + cs;
    const float q0 = qp[0], q1v = qp[1], q2v = qp[2], q3v = qp[3], q4v = qp[4];

    float accD = 0.f, aN0 = 0.f, aN1 = 0.f, aN2 = 0.f, aN3 = 0.f, aN4 = 0.f;
    const int nit = (deg + 5) / 6;
    int i = slot;
    bool val = active && (i < deg);
    int e = 0, s = 0;
    if (val) { e = seid[p0 + i]; s = ssrc[p0 + i]; }
    for (int t = 0; t < nit; ++t) {
      int in = i + 6;
      bool valn = active && (in < deg);
      int en = 0, sn = 0;
      if (valn) { en = seid[p0 + in]; sn = ssrc[p0 + in]; }
      float ev0 = 0.f, ev1 = 0.f, ev2 = 0.f, ev3 = 0.f, ev4 = 0.f;
      float k0 = 0.f, k1 = 0.f, k2 = 0.f, k3 = 0.f, k4 = 0.f;
      float v0 = 0.f, v1 = 0.f, v2 = 0.f, v3 = 0.f, v4 = 0.f;
      if (val) {
        const unsigned int* er = evu + (size_t)e * 32 + (cs >> 1);
        unsigned int u0 = er[0], u1 = er[1], u2 = er[2];
        if (cs & 1) {
          ev0 = f16_to_f32((unsigned short)(u0 >> 16));
          ev1 = f16_to_f32((unsigned short)(u1 & 0xffff));
          ev2 = f16_to_f32((unsigned short)(u1 >> 16));
          ev3 = f16_to_f32((unsigned short)(u2 & 0xffff));
          ev4 = f16_to_f32((unsigned short)(u2 >> 16));
        } else {
          ev0 = f16_to_f32((unsigned short)(u0 & 0xffff));
          ev1 = f16_to_f32((unsigned short)(u0 >> 16));
          ev2 = f16_to_f32((unsigned short)(u1 & 0xffff));
          ev3 = f16_to_f32((unsigned short)(u1 >> 16));
          ev4 = f16_to_f32((unsigned short)(u2 & 0xffff));
        }
        // kv1h row: [k0,v0,k1,v1,...] f16; head h -> shorts [10h..10h+9]
        const unsigned int* kvp =
            (const unsigned int*)(kv1h + (size_t)s * 104 + 10 * h);
        unsigned int a0 = kvp[0], a1 = kvp[1], a2 = kvp[2], a3 = kvp[3], a4 = kvp[4];
        k0 = f16_to_f32((unsigned short)(a0 & 0xffff)); v0 = f16_to_f32((unsigned short)(a0 >> 16));
        k1 = f16_to_f32((unsigned short)(a1 & 0xffff)); v1 = f16_to_f32((unsigned short)(a1 >> 16));
        k2 = f16_to_f32((unsigned short)(a2 & 0xffff)); v2 = f16_to_f32((unsigned short)(a2 >> 16));
        k3 = f16_to_f32((unsigned short)(a3 & 0xffff)); v3 = f16_to_f32((unsigned short)(a3 >> 16));
        k4 = f16_to_f32((unsigned short)(a4 & 0xffff)); v4 = f16_to_f32((unsigned short)(a4 >> 16));
      }
      float al = q0 * (k0 + ev0);
      al = fmaf(q1v, k1 + ev1, al);
      al = fmaf(q2v, k2 + ev2, al);
      al = fmaf(q3v, k3 + ev3, al);
      al = fmaf(q4v, k4 + ev4, al);
      float ex = val ? __expf(al * INV_SQRT5) : 0.f;
      accD += ex;
      aN0 = fmaf(v0 + ev0, ex, aN0);
      aN1 = fmaf(v1 + ev1, ex, aN1);
      aN2 = fmaf(v2 + ev2, ex, aN2);
      aN3 = fmaf(v3 + ev3, ex, aN3);
      aN4 = fmaf(v4 + ev4, ex, aN4);
      i = in; val = valn; e = en; s = sn;
    }
    // slot-reduce (6 slots) for this lane's head
    float D = 0.f, N0 = 0.f, N1 = 0.f, N2 = 0.f, N3 = 0.f, N4 = 0.f;
#pragma unroll
    for (int i2 = 0; i2 < 6; ++i2) {
      int sl = h + 10 * i2;
      D  += __shfl(accD, sl);
      N0 += __shfl(aN0, sl); N1 += __shfl(aN1, sl); N2 += __shfl(aN2, sl);
      N3 += __shfl(aN3, sl); N4 += __shfl(aN4, sl);
    }
    float rD = (D > 0.f) ? (1.f / D) : 0.f;
    float r0 = N0 * rD, r1 = N1 * rD, r2 = N2 * rD, r3 = N3 * rD, r4 = N4 * rD;
    // head-mean (10 heads live on lanes 0..9)
    float o0 = 0.f, o1 = 0.f, o2 = 0.f, o3 = 0.f, o4 = 0.f;
#pragma unroll
    for (int hh = 0; hh < 10; ++hh) {
      o0 += __shfl(r0, hh); o1 += __shfl(r1, hh); o2 += __shfl(r2, hh);
      o3 += __shfl(r3, hh); o4 += __shfl(r4, hh);
    }
    o0 *= 0.1f; o1 *= 0.1f; o2 *= 0.1f; o3 *= 0.1f; o4 *= 0.1f;
    float4 xv = *(const float4*)(xr1 + (size_t)n * 8);
    float x4 = xr1[(size_t)n * 8 + 4];
    float sb = bw0[0] * o0 + bw1[0] * xv.x + bw2[0] * (o0 - xv.x);
    sb += bw0[1] * o1 + bw1[1] * xv.y + bw2[1] * (o1 - xv.y);
    sb += bw0[2] * o2 + bw1[2] * xv.z + bw2[2] * (o2 - xv.z);
    sb += bw0[3] * o3 + bw1[3] * xv.w + bw2[3] * (o3 - xv.w);
    sb += bw0[4] * o4 + bw1[4] * x4 + bw2[4] * (o4 - x4);
    float beta = 1.f / (1.f + __expf(-sb));
    if (lane < 5) {
      float ow = (lane == 0) ? o0 : (lane == 1) ? o1 : (lane == 2) ? o2
               : (lane == 3) ? o3 : o4;
      float xw = (lane == 0) ? xv.x : (lane == 1) ? xv.y : (lane == 2) ? xv.z
               : (lane == 3) ? xv.w : x4;
      h1[(size_t)n * 8 + lane] = beta * xw + (1.f - beta) * ow;
    }
  }
}

// ---- GraphNorm stats, single pass (sum, sumsq, count) ----------------------
__global__ __launch_bounds__(256) void k_stats(
    const float* __restrict__ h1, const int* __restrict__ batch,
    float* __restrict__ gsum, float* __restrict__ gsq,
    float* __restrict__ gcnt, int n_nodes) {
  int n = blockIdx.x * 256 + threadIdx.x;
  bool act = n < n_nodes;
  int g = act ? batch[n] : 0;
  float v[5], s2[5], one = act ? 1.f : 0.f;
#pragma unroll
  for (int c = 0; c < 5; ++c) {
    v[c] = act ? h1[(size_t)n * 8 + c] : 0.f;
    s2[c] = v[c] * v[c];
  }
  int g0 = __shfl(g, 0);
  bool uni = __all((!act) || (g == g0));
  if (uni) {
#pragma unroll
    for (int off = 32; off; off >>= 1) {
#pragma unroll
      for (int c = 0; c < 5; ++c) {
        v[c] += __shfl_down(v[c], off);
        s2[c] += __shfl_down(s2[c], off);
      }
      one += __shfl_down(one, off);
    }
    if ((threadIdx.x & 63) == 0) {
#pragma unroll
      for (int c = 0; c < 5; ++c) {
        atomicAdd(&gsum[g0 * 8 + c], v[c]);
        atomicAdd(&gsq[g0 * 8 + c], s2[c]);
      }
      atomicAdd(&gcnt[g0], one);
    }
  } else if (act) {
#pragma unroll
    for (int c = 0; c < 5; ++c) {
      atomicAdd(&gsum[g * 8 + c], v[c]);
      atomicAdd(&gsq[g * 8 + c], s2[c]);
    }
    atomicAdd(&gcnt[g], 1.f);
  }
}

// ---- apply norm + relu + q2/kv2/xr2 (kv2 stored f16) -----------------------
__global__ __launch_bounds__(256) void k_apply(
    const float* __restrict__ h1, const int* __restrict__ batch,
    const float* __restrict__ gsum, const float* __restrict__ gsq,
    const float* __restrict__ gcnt,
    const float* __restrict__ gnw, const float* __restrict__ gnb,
    const float* __restrict__ gnms,
    const float* __restrict__ q2W, const float* __restrict__ q2b,
    const float* __restrict__ k2W, const float* __restrict__ k2b,
    const float* __restrict__ v2W, const float* __restrict__ v2b,
    const float* __restrict__ s2W, const float* __restrict__ s2b,
    float* __restrict__ q2, unsigned short* __restrict__ kv2h,
    float* __restrict__ xr2, int n_nodes) {
  int n = blockIdx.x * 256 + threadIdx.x;
  if (n >= n_nodes) return;
  int g = batch[n];
  float rc = 1.f / fmaxf(gcnt[g], 1.f);
  float r[5];
#pragma unroll
  for (int c = 0; c < 5; ++c) {
    float ms = gnms[c];
    float mean = gsum[g * 8 + c] * rc;
    float var = gsq[g * 8 + c] * rc - mean * mean * ms * (2.f - ms);
    var = fmaxf(var, 0.f);
    float o = h1[(size_t)n * 8 + c] - mean * ms;
    float y = gnw[c] * o * rsqrtf(var + EPS) + gnb[c];
    r[c] = fmaxf(y, 0.f);
  }
#pragma unroll
  for (int h = 0; h < 10; ++h) {
    float aq = q2b[h], ak = k2b[h], av = v2b[h];
#pragma unroll
    for (int i = 0; i < 5; ++i) {
      aq = fmaf(r[i], q2W[h * 5 + i], aq);
      ak = fmaf(r[i], k2W[h * 5 + i], ak);
      av = fmaf(r[i], v2W[h * 5 + i], av);
    }
    q2[(size_t)n * 12 + h] = aq;
    union { _Float16 hh[2]; unsigned int u; } p;
    p.hh[0] = (_Float16)ak; p.hh[1] = (_Float16)av;
    *(unsigned int*)(kv2h + (size_t)n * 24 + 2 * h) = p.u;
  }
  float s = s2b[0];
#pragma unroll
  for (int i = 0; i < 5; ++i) s = fmaf(r[i], s2W[i], s);
  xr2[n] = s;
}

// ---- K-conv2: persistent wave per node, 6 edges x 10 heads, f16 kv ---------
__global__ __launch_bounds__(256) void k_conv2(
    const int* __restrict__ rp, const int* __restrict__ seid,
    const int* __restrict__ ssrc, const float* __restrict__ attr,
    const float* __restrict__ q2, const unsigned short* __restrict__ kv2h,
    const float* __restrict__ xr2,
    const float* __restrict__ bW, float* __restrict__ out, int n_nodes) {
  const int lane = threadIdx.x & 63;
  const int wid = (blockIdx.x * 256 + threadIdx.x) >> 6;
  const int nw = gridDim.x * 4;
  const int slot = lane / 10, h = lane - slot * 10;
  const bool active = slot < 6;
  const unsigned short* evr = (const unsigned short*)attr;

  for (int n = wid; n < n_nodes; n += nw) {
    int p0 = rp[n], deg = rp[n + 1] - p0;
    float qh = q2[(size_t)n * 12 + h];
    int eL = 0, sL = 0;
    if (lane < deg) { eL = seid[p0 + lane]; sL = ssrc[p0 + lane]; }
    float accN = 0.f, accD = 0.f;
    int nit = (deg + 5) / 6;
    for (int t = 0; t < nit; ++t) {
      int i = t * 6 + slot;
      bool val = active && (i < deg);
      int e = 0, s = 0;
      if (i < 64) { e = __shfl(eL, i); s = __shfl(sL, i); }
      else if (val) { e = seid[p0 + i]; s = ssrc[p0 + i]; }
      float evv = 0.f, kx = 0.f, ky = 0.f;
      if (val) {
        evv = f16_to_f32(evr[(size_t)e * 64 + 50 + h]);
        unsigned int u = *(const unsigned int*)(kv2h + (size_t)s * 24 + 2 * h);
        kx = f16_to_f32((unsigned short)(u & 0xffff));
        ky = f16_to_f32((unsigned short)(u >> 16));
      }
      float exv = val ? __expf(qh * (kx + evv)) : 0.f;
      accD += exv;
      accN = fmaf(ky + evv, exv, accN);
    }
    float D = 0.f, Nn = 0.f;
#pragma unroll
    for (int i2 = 0; i2 < 6; ++i2) {
      D  += __shfl(accD, h + 10 * i2);
      Nn += __shfl(accN, h + 10 * i2);
    }
    float r = (D > 0.f) ? Nn / D : 0.f;
    float o = 0.f;
#pragma unroll
    for (int j = 0; j < 10; ++j) o += __shfl(r, j);
    o *= 0.1f;
    float xr = xr2[n];
    float sbv = bW[0] * o + bW[1] * xr + bW[2] * (o - xr);
    float beta = 1.f / (1.f + __expf(-sbv));
    float y = beta * xr + (1.f - beta) * o;
    if (lane == 0) out[n] = 1.f / (1.f + __expf(-y));
  }
}

// ---------------------------------------------------------------------------
extern "C" void kernel_launch(void* const* d_in, const int* in_sizes, int n_in,
                              void* d_out, int out_size, void* d_ws, size_t ws_size,
                              hipStream_t stream) {
  const float* x    = (const float*)d_in[0];
  float*       attr = (float*)d_in[1];          // overwritten in-place by k_evt
  const int*   ei   = (const int*)d_in[2];
  const int*   batch= (const int*)d_in[3];
  const float* q1W = (const float*)d_in[4];  const float* q1b = (const float*)d_in[5];
  const float* k1W = (const float*)d_in[6];  const float* k1b = (const float*)d_in[7];
  const float* v1W = (const float*)d_in[8];  const float* v1b = (const float*)d_in[9];
  const float* e1W = (const float*)d_in[10];
  const float* s1W = (const float*)d_in[11]; const float* s1b = (const float*)d_in[12];
  const float* b1W = (const float*)d_in[13];
  const float* gnW = (const float*)d_in[14]; const float* gnb = (const float*)d_in[15];
  const float* gnms= (const float*)d_in[16];
  const float* q2W = (const float*)d_in[17]; const float* q2b = (const float*)d_in[18];
  const float* k2W = (const float*)d_in[19]; const float* k2b = (const float*)d_in[20];
  const float* v2W = (const float*)d_in[21]; const float* v2b = (const float*)d_in[22];
  const float* e2W = (const float*)d_in[23];
  const float* s2W = (const float*)d_in[24]; const float* s2b = (const float*)d_in[25];
  const float* b2W = (const float*)d_in[26];

  const int n_nodes = in_sizes[0] / 128;
  const int n_edges = in_sizes[2] / 2;
  float* ws = (float*)d_ws;
  const size_t nn = (size_t)n_nodes;
  const size_t ne = (size_t)n_edges;

  // workspace layout (float units)
  const size_t oQ1  = 0;              // 52*nn
  const size_t oKV1 = 52 * nn;        // 52*nn (104 f16/node, k/v interleaved)
  const size_t oXR1 = 104 * nn;       // 8*nn
  const size_t oH1  = 112 * nn;       // 8*nn
  const size_t oQ2  = 120 * nn;       // 12*nn
  const size_t oKV2 = 132 * nn;       // 12*nn (24 f16/node)
  const size_t oXR2 = 144 * nn;       // nn
  const size_t oSTAT= 145 * nn;       // 1088 (gsum 512 | gsq 512 | gcnt 64)
  const size_t oCNT = oSTAT + 1088;   // nn ints (contiguous with STAT: 1 memset)
  const size_t oRP  = oCNT + nn;      // nn+1 ints
  const size_t oCUR = oRP + nn + 4;   // nn ints (padded so base stays 16B-aligned)
  const size_t oSEID= oCUR + nn;      // ne ints
  const size_t oSSRC= oSEID + ne;     // ne ints
  const size_t oBSUM= oSSRC + ne;     // ~128 ints (scan block sums)

  int* cnt    = (int*)(ws + oCNT);
  int* rp     = (int*)(ws + oRP);
  int* cursor = (int*)(ws + oCUR);
  int* seid   = (int*)(ws + oSEID);
  int* ssrc   = (int*)(ws + oSSRC);
  int* bsum   = (int*)(ws + oBSUM);
  float* gsum = ws + oSTAT;
  float* gsq  = ws + oSTAT + 512;
  float* gcnt = ws + oSTAT + 1024;
  unsigned short* kv1h = (unsigned short*)(ws + oKV1);
  unsigned short* kv2h = (unsigned short*)(ws + oKV2);

  const int nb_nodes = (n_nodes + 255) / 256;
  const int nb_edges = (n_edges + 255) / 256;
  const int nb_scan  = (n_nodes + 1023) / 1024;   // 98 for N=100000 (<=256)
  dim3 gq(4, (n_nodes + 511) / 512);  // g fast -> siblings co-resident
  const int nb_pers = 2048;  // persistent-wave grid for conv kernels

  // one memset covers stats (1088 f) + cnt (nn ints)
  hipMemsetAsync(ws + oSTAT, 0, (1088 + nn) * sizeof(float), stream);

  k_hist<<<nb_edges, 256, 0, stream>>>(ei, n_edges, cnt);
  k_scansum<<<nb_scan, 256, 0, stream>>>(cnt, bsum, n_nodes);
  k_scantop<<<1, 256, 0, stream>>>(bsum, nb_scan);
  k_scanout<<<nb_scan, 256, 0, stream>>>(cnt, bsum, rp, cursor, n_nodes);
  k_scatter<<<nb_edges, 256, 0, stream>>>(ei, n_edges, cursor, seid, ssrc);

  k_qkvs1<<<gq, 256, 0, stream>>>(x, q1W, q1b, k1W, k1b, v1W, v1b, s1W, s1b,
                                  ws + oQ1, kv1h, ws + oXR1, n_nodes);
  k_evt<<<nb_edges, 256, 0, stream>>>(attr, e1W, e2W, n_edges);

  k_conv1<<<nb_pers, 256, 0, stream>>>(rp, seid, ssrc, attr,
                                       ws + oQ1, kv1h, ws + oXR1,
                                       b1W, ws + oH1, n_nodes);
  k_stats<<<nb_nodes, 256, 0, stream>>>(ws + oH1, batch, gsum, gsq, gcnt, n_nodes);
  k_apply<<<nb_nodes, 256, 0, stream>>>(ws + oH1, batch, gsum, gsq, gcnt,
                                        gnW, gnb, gnms,
                                        q2W, q2b, k2W, k2b, v2W, v2b, s2W, s2b,
                                        ws + oQ2, kv2h, ws + oXR2, n_nodes);
  k_conv2<<<nb_pers, 256, 0, stream>>>(rp, seid, ssrc, attr,
                                       ws + oQ2, kv2h, ws + oXR2,
                                       b2W, (float*)d_out, n_nodes);
}